// Round 13
// baseline (432.317 us; speedup 1.0000x reference)
//
#include <hip/hip_runtime.h>
#include <hip/hip_bf16.h>
#include <cstdint>

typedef __attribute__((ext_vector_type(8))) short bf16x8;
typedef __attribute__((ext_vector_type(4))) float f32x4;
typedef __attribute__((ext_vector_type(8))) unsigned short u16x8;

__device__ __forceinline__ unsigned short f2bf(float f) {
    unsigned int u = __float_as_uint(f);
    unsigned int r = (u + 0x7fffu + ((u >> 16) & 1u)) >> 16;
    return (unsigned short)r;
}

__device__ __forceinline__ float tanh_fast(float x) {
    return 1.0f - 2.0f / (__expf(2.0f * x) + 1.0f);
}

#define GLDS(SRC, DST) __builtin_amdgcn_global_load_lds(                         \
        (const __attribute__((address_space(1))) void*)(SRC),                    \
        (__attribute__((address_space(3))) void*)(DST), 16, 0, 0)

// ---------- K-1: key fp32 -> bf16, tiled for the BK=64 pipeline ----------
// per (panel p: 256 rows, K-tile kt: 64 k): 2048 chunks of 16B,
// chunk c = kh*1024 + hf*512 + mfg*64 + (ks<<4 | row15)
// holds row p*256+hf*128+mfg*16+row15, k kt*64+kh*32+ks*8 .. +8
__global__ __launch_bounds__(512) void key_tile_kernel(
        const float* __restrict__ in, unsigned short* __restrict__ out) {
    const int p = blockIdx.x;   // 0..255
    const int kt = blockIdx.y;  // 0..15
    const int t = threadIdx.x;
    const int lrow = t >> 2, ks = t & 3;
#pragma unroll
    for (int pass = 0; pass < 4; ++pass) {
        const int hf = pass >> 1, kh = pass & 1;
        const int row = p * 256 + hf * 128 + lrow;
        const int k = kt * 64 + kh * 32 + ks * 8;
        const float* src = in + (size_t)row * 1024 + k;
        const float4 v0 = *reinterpret_cast<const float4*>(src);
        const float4 v1 = *reinterpret_cast<const float4*>(src + 4);
        u16x8 u;
        u[0] = f2bf(v0.x); u[1] = f2bf(v0.y); u[2] = f2bf(v0.z); u[3] = f2bf(v0.w);
        u[4] = f2bf(v1.x); u[5] = f2bf(v1.y); u[6] = f2bf(v1.z); u[7] = f2bf(v1.w);
        const int c = kh * 1024 + hf * 512 + (lrow >> 4) * 64 + (ks << 4) + (lrow & 15);
        *reinterpret_cast<u16x8*>(out + ((size_t)(p * 16 + kt) * 2048 + c) * 8) = u;
    }
}

// ---------- K0: w_v -> bf16 tiled B for BK=64 ----------
// per (hp, kt): 2048 chunks; chunk = kh*1024 + hfB*512 + cbg*64 + lane
// holds col e = hp*256+hfB*128+cbg*16+(lane&15), k f = kt*64+kh*32+(lane>>4)*8
__global__ __launch_bounds__(256) void wv_tile_kernel(
        const float* __restrict__ wv, unsigned short* __restrict__ out) {
    __shared__ float tile[64][130];
    const int h = blockIdx.x;    // 0..7
    const int kt = blockIdx.y;   // 0..15
    const int hp = h >> 1, hfB = h & 1;
    const int t = threadIdx.x;
    for (int i = t; i < 2048; i += 256) {           // 64 f x 32 float4
        const int f = i >> 5, e4 = (i & 31) * 4;
        const float4 v = *reinterpret_cast<const float4*>(
            wv + (size_t)(kt * 64 + f) * 1024 + hp * 256 + hfB * 128 + e4);
        tile[f][e4 + 0] = v.x; tile[f][e4 + 1] = v.y;
        tile[f][e4 + 2] = v.z; tile[f][e4 + 3] = v.w;
    }
    __syncthreads();
#pragma unroll
    for (int cc = 0; cc < 4; ++cc) {
        const int c = cc * 256 + t;                 // 0..1023
        const int kh = c >> 9, cbg = (c >> 6) & 7, lane = c & 63;
        u16x8 u;
#pragma unroll
        for (int jj = 0; jj < 8; ++jj)
            u[jj] = f2bf(tile[kh * 32 + (lane >> 4) * 8 + jj][cbg * 16 + (lane & 15)]);
        *reinterpret_cast<u16x8*>(out + ((size_t)(hp * 16 + kt) * 2048
                                         + kh * 1024 + hfB * 512 + cbg * 64 + lane) * 8) = u;
    }
}

// ---------- K1: q projection ----------
__global__ __launch_bounds__(1024) void qproj_kernel(
        const float* __restrict__ query, const float* __restrict__ w_q,
        float* __restrict__ ws_q) {
    __shared__ float qs[1024];
    const int b = blockIdx.x;
    const int t = threadIdx.x;
    qs[t] = query[(size_t)b * 1024 + t];
    __syncthreads();
    float acc = 0.f;
    const float* w = w_q + t;
#pragma unroll 8
    for (int f = 0; f < 1024; ++f) acc = fmaf(qs[f], w[(size_t)f * 1024], acc);
    ws_q[(size_t)b * 1024 + t] = acc;
}

// ---------- K2: conv1d location features ----------
__global__ __launch_bounds__(256) void loc_conv_kernel(
        const float* __restrict__ pa, const float* __restrict__ conv_w,
        const float* __restrict__ conv_b, float* __restrict__ ws_loc) {
    __shared__ float pas[8][258];
    __shared__ float cw[240];
    __shared__ float cb[16];
    int b = blockIdx.x, k0 = blockIdx.y * 256;
    int t = threadIdx.x;
    for (int i = t; i < 8 * 258; i += 256) {
        int hh = i / 258, kk = i % 258;
        int gk = k0 + kk - 1;
        pas[hh][kk] = (gk >= 0 && gk < 4096) ? pa[((size_t)(b * 8 + hh)) * 4096 + gk] : 0.f;
    }
    if (t < 240) cw[t] = conv_w[t];
    if (t < 10) cb[t] = conv_b[t];
    __syncthreads();
#pragma unroll
    for (int c = 0; c < 10; ++c) {
        float acc = cb[c];
#pragma unroll
        for (int hh = 0; hh < 8; ++hh) {
            acc += pas[hh][t] * cw[(c * 8 + hh) * 3 + 0]
                 + pas[hh][t + 1] * cw[(c * 8 + hh) * 3 + 1]
                 + pas[hh][t + 2] * cw[(c * 8 + hh) * 3 + 2];
        }
        ws_loc[((size_t)(b * 10 + c)) * 4096 + k0 + t] = acc;
    }
}

// ---------- K2b: le[b,k,d] = tanh(sum_c loc[b,c,k]*w_u[c,d]) ----------
__global__ __launch_bounds__(256) void loc_energy_kernel(
        const float* __restrict__ ws_loc, const float* __restrict__ w_u,
        float* __restrict__ le) {
    __shared__ float loc_s[10][128];
    __shared__ float wu_s[10][128];
    const int b = blockIdx.x, k0 = blockIdx.y * 128;
    const int t = threadIdx.x;
    for (int i = t; i < 1280; i += 256) {
        const int c = i >> 7, r = i & 127;
        loc_s[c][r] = ws_loc[((size_t)(b * 10 + c)) * 4096 + k0 + r];
        wu_s[c][r] = w_u[i];
    }
    __syncthreads();
    const int k = t >> 1;
    const int d0 = (t & 1) * 64;
    float lc[10];
#pragma unroll
    for (int c = 0; c < 10; ++c) lc[c] = loc_s[c][k];
    float* dst = le + ((size_t)(b * 4096) + k0 + k) * 128 + d0;
#pragma unroll
    for (int dd = 0; dd < 64; dd += 4) {
        float4 o;
#pragma unroll
        for (int jj = 0; jj < 4; ++jj) {
            float s = 0.f;
#pragma unroll
            for (int c = 0; c < 10; ++c) s += lc[c] * wu_s[c][d0 + dd + jj];
            ((float*)&o)[jj] = tanh_fast(s);
        }
        *reinterpret_cast<float4*>(dst + dd) = o;
    }
}

// ---------- K3: counted-vmcnt deep-pipelined bf16 MFMA GEMM + score ----------
// BM=256, BN=256 (2 heads), BK=64; 512 thr, 8 waves (2M x 4N), wave 128x64.
// Pure global_load_lds both operands; 4 half-tile stages per K-tile issued one
// per phase, consumed 4 phases later; vmcnt(6) + barrier at p0/p2 only; NO
// vmcnt(0)/lgkmcnt(0) drains in the loop. acc[8][4], 1 block/CU (128KB LDS).
#define NKT 16
__global__ __launch_bounds__(512, 2) void gemm_score_kernel(
        const unsigned short* __restrict__ keyT, const unsigned short* __restrict__ wvT,
        const float* __restrict__ le,
        const float* __restrict__ ws_q, const float* __restrict__ bias,
        const float* __restrict__ score_w, const float* __restrict__ score_b,
        float* __restrict__ align_out) {
    __shared__ __align__(16) unsigned short As[2][16384];   // 64 KB
    __shared__ __align__(16) unsigned short Bs[2][16384];   // 64 KB
    __shared__ float qb_sm[256], sw_sm[128];
    __shared__ float partial[256][4];

    const int t = threadIdx.x;
    const int lane = t & 63, wid = t >> 6;
    const int wm = wid >> 2;          // 0..1 : 128-row half
    const int wn = wid & 3;           // 0..3 : (head, d-half)

    // XCD swizzle: 4 head-pair blocks of one 256-row panel adjacent on one XCD
    const int fid = blockIdx.x;       // 0..1023
    const int x = fid & 7, j = fid >> 3;
    const int bm = x * 32 + (j >> 2);        // panel 0..255
    const int hp = j & 3;
    const int b = bm >> 4;
    const int kk0 = (bm & 15) << 8;

    if (t < 256) {
        const int hh = t >> 7, d = t & 127;
        qb_sm[t] = ws_q[(size_t)(b * 8 + hp * 2 + hh) * 128 + d] + bias[d];
        if (t < 128) sw_sm[t] = score_w[t];
    }

    const unsigned short* aT = keyT + (size_t)(bm * 16) * 16384;
    const unsigned short* bT = wvT + (size_t)(hp * 16) * 16384;

    // one half-tile = 16 KB = 1024 chunks; thread stages chunks t and t+512
#define SA(BUF, KT, KH) {                                                         \
        const unsigned short* s_ = aT + (size_t)(KT) * 16384 + (KH) * 8192;       \
        GLDS(s_ + t * 8, &As[BUF][(KH) * 8192 + t * 8]);                          \
        GLDS(s_ + 4096 + t * 8, &As[BUF][(KH) * 8192 + 4096 + t * 8]); }
#define SB(BUF, KT, KH) {                                                         \
        const unsigned short* s_ = bT + (size_t)(KT) * 16384 + (KH) * 8192;       \
        GLDS(s_ + t * 8, &Bs[BUF][(KH) * 8192 + t * 8]);                          \
        GLDS(s_ + 4096 + t * 8, &Bs[BUF][(KH) * 8192 + 4096 + t * 8]); }

    f32x4 acc[8][4] = {};

    // prologue: stage kt0's 4 half-tiles in consumption order
    SA(0, 0, 0); SB(0, 0, 0); SA(0, 0, 1); SB(0, 0, 1);

    for (int kt = 0; kt < NKT; ++kt) {
        const int cur = kt & 1, nxt = cur ^ 1;
        const int nk = (kt + 1) & (NKT - 1);   // kt=15 re-stages kt0 (never read)
        bf16x8 bg[4], af[4];

        // ---- p0: stage A-kh0(next); certify kh0(cur); compute mf0-3 x kh0 ----
        SA(nxt, nk, 0);
        asm volatile("s_waitcnt vmcnt(6)\n\ts_barrier" ::: "memory");
#pragma unroll
        for (int nf = 0; nf < 4; ++nf)
            bg[nf] = *reinterpret_cast<const bf16x8*>(
                &Bs[cur][((wn >> 1) * 512 + ((wn & 1) * 4 + nf) * 64 + lane) * 8]);
#pragma unroll
        for (int mf = 0; mf < 4; ++mf)
            af[mf] = *reinterpret_cast<const bf16x8*>(
                &As[cur][(wm * 512 + mf * 64 + lane) * 8]);
        __builtin_amdgcn_s_setprio(1);
#pragma unroll
        for (int mf = 0; mf < 4; ++mf)
#pragma unroll
            for (int nf = 0; nf < 4; ++nf)
                acc[mf][nf] = __builtin_amdgcn_mfma_f32_16x16x32_bf16(
                    af[mf], bg[nf], acc[mf][nf], 0, 0, 0);
        __builtin_amdgcn_s_setprio(0);

        // ---- p1: stage B-kh0(next); compute mf4-7 x kh0 (no barrier needed) ----
        SB(nxt, nk, 0);
#pragma unroll
        for (int mf = 0; mf < 4; ++mf)
            af[mf] = *reinterpret_cast<const bf16x8*>(
                &As[cur][(wm * 512 + (4 + mf) * 64 + lane) * 8]);
        __builtin_amdgcn_s_setprio(1);
#pragma unroll
        for (int mf = 0; mf < 4; ++mf)
#pragma unroll
            for (int nf = 0; nf < 4; ++nf)
                acc[4 + mf][nf] = __builtin_amdgcn_mfma_f32_16x16x32_bf16(
                    af[mf], bg[nf], acc[4 + mf][nf], 0, 0, 0);
        __builtin_amdgcn_s_setprio(0);

        // ---- p2: stage A-kh1(next); certify kh1(cur); compute mf0-3 x kh1 ----
        SA(nxt, nk, 1);
        asm volatile("s_waitcnt vmcnt(6)\n\ts_barrier" ::: "memory");
#pragma unroll
        for (int nf = 0; nf < 4; ++nf)
            bg[nf] = *reinterpret_cast<const bf16x8*>(
                &Bs[cur][(1024 + (wn >> 1) * 512 + ((wn & 1) * 4 + nf) * 64 + lane) * 8]);
#pragma unroll
        for (int mf = 0; mf < 4; ++mf)
            af[mf] = *reinterpret_cast<const bf16x8*>(
                &As[cur][(1024 + wm * 512 + mf * 64 + lane) * 8]);
        __builtin_amdgcn_s_setprio(1);
#pragma unroll
        for (int mf = 0; mf < 4; ++mf)
#pragma unroll
            for (int nf = 0; nf < 4; ++nf)
                acc[mf][nf] = __builtin_amdgcn_mfma_f32_16x16x32_bf16(
                    af[mf], bg[nf], acc[mf][nf], 0, 0, 0);
        __builtin_amdgcn_s_setprio(0);

        // ---- p3: stage B-kh1(next); compute mf4-7 x kh1 ----
        SB(nxt, nk, 1);
#pragma unroll
        for (int mf = 0; mf < 4; ++mf)
            af[mf] = *reinterpret_cast<const bf16x8*>(
                &As[cur][(1024 + wm * 512 + (4 + mf) * 64 + lane) * 8]);
        __builtin_amdgcn_s_setprio(1);
#pragma unroll
        for (int mf = 0; mf < 4; ++mf)
#pragma unroll
            for (int nf = 0; nf < 4; ++nf)
                acc[4 + mf][nf] = __builtin_amdgcn_mfma_f32_16x16x32_bf16(
                    af[mf], bg[nf], acc[4 + mf][nf], 0, 0, 0);
        __builtin_amdgcn_s_setprio(0);
    }

    // ---- epilogue: score = sum_d tanh(kproj + q + bias + le) * sw ----
    const float K2 = 2.8853900817779268f;
    const float sb = score_b[0];
    const int g = lane >> 4;
    const int l15 = lane & 15;
    float kqb[4], swv[4];
#pragma unroll
    for (int nf = 0; nf < 4; ++nf) {
        const int d128 = (wn & 1) * 64 + nf * 16 + l15;
        kqb[nf] = qb_sm[(wn >> 1) * 128 + d128] * K2;
        swv[nf] = sw_sm[d128];
    }
    const float* leB = le + ((size_t)(b * 4096 + kk0) + wm * 128 + g * 4) * 128
                       + (wn & 1) * 64 + l15;

#pragma unroll
    for (int mf = 0; mf < 8; ++mf) {
        float lv[16];
#pragma unroll
        for (int jj = 0; jj < 4; ++jj)
#pragma unroll
            for (int nf = 0; nf < 4; ++nf)
                lv[jj * 4 + nf] = leB[(size_t)(mf * 16 + jj) * 128 + nf * 16];
#pragma unroll
        for (int jj = 0; jj < 4; ++jj) {
            const int row_l = wm * 128 + mf * 16 + g * 4 + jj;
            float sum = 0.f;
#pragma unroll
            for (int nf = 0; nf < 4; ++nf) {
                const float m = fmaf(K2, lv[jj * 4 + nf], kqb[nf]);
                const float tt = fmaf(K2, acc[mf][nf][jj], m);
                const float y = __builtin_amdgcn_exp2f(tt);
                const float r = fmaf(-2.0f, __builtin_amdgcn_rcpf(y + 1.0f), 1.0f);
                sum = fmaf(r, swv[nf], sum);
            }
            sum += __shfl_xor(sum, 1);
            sum += __shfl_xor(sum, 2);
            sum += __shfl_xor(sum, 4);
            sum += __shfl_xor(sum, 8);
            if (l15 == 0) partial[row_l][wn] = sum;
        }
    }
    __syncthreads();
    if (t < 512) {
        const int r = t >> 1, hh = t & 1;
        const float sc = partial[r][hh * 2] + partial[r][hh * 2 + 1] + sb;
        align_out[(size_t)(b * 8 + hp * 2 + hh) * 4096 + kk0 + r] = sc;
    }
}

// ---------- K4: softmax over k ----------
__global__ __launch_bounds__(256) void softmax_kernel(float* __restrict__ align_o) {
    const int bh = blockIdx.x;
    float* row = align_o + (size_t)bh * 4096;
    const int t = threadIdx.x;
    float v[16];
    float m = -1e30f;
#pragma unroll
    for (int i = 0; i < 16; ++i) {
        v[i] = row[i * 256 + t];
        m = fmaxf(m, v[i]);
    }
#pragma unroll
    for (int off = 32; off; off >>= 1) m = fmaxf(m, __shfl_xor(m, off));
    __shared__ float sm[4], ss[4];
    const int wid = t >> 6;
    if ((t & 63) == 0) sm[wid] = m;
    __syncthreads();
    m = fmaxf(fmaxf(sm[0], sm[1]), fmaxf(sm[2], sm[3]));
    float s = 0.f;
#pragma unroll
    for (int i = 0; i < 16; ++i) {
        v[i] = __expf(v[i] - m);
        s += v[i];
    }
#pragma unroll
    for (int off = 32; off; off >>= 1) s += __shfl_xor(s, off);
    if ((t & 63) == 0) ss[wid] = s;
    __syncthreads();
    s = ss[0] + ss[1] + ss[2] + ss[3];
    const float inv = 1.f / s;
#pragma unroll
    for (int i = 0; i < 16; ++i) row[i * 256 + t] = v[i] * inv;
}

// ---------- K5: split-K context partials ----------
__global__ __launch_bounds__(256) void ctx_partial_kernel(
        const float* __restrict__ value, const float* __restrict__ align_o,
        float* __restrict__ pctx) {
    const int s = blockIdx.x;    // 0..31
    const int bh = blockIdx.y;   // 0..127
    const int b = bh >> 3, h = bh & 7;
    const int t = threadIdx.x;
    const int d4 = (t & 31) * 4;
    const int kg = t >> 5;
    const float* arow = align_o + (size_t)bh * 4096 + s * 128;
    const float* vbase = value + ((size_t)(b * 4096 + s * 128)) * 1024 + h * 128 + d4;
    float4 acc = {0.f, 0.f, 0.f, 0.f};
    for (int i = 0; i < 16; ++i) {
        const int kk = i * 8 + kg;
        const float a = arow[kk];
        const float4 v = *reinterpret_cast<const float4*>(vbase + (size_t)kk * 1024);
        acc.x += a * v.x; acc.y += a * v.y; acc.z += a * v.z; acc.w += a * v.w;
    }
    __shared__ float sm2[8][128];
    *reinterpret_cast<float4*>(&sm2[kg][d4]) = acc;
    __syncthreads();
    if (t < 128) {
        float s0 = 0.f;
#pragma unroll
        for (int gg = 0; gg < 8; ++gg) s0 += sm2[gg][t];
        pctx[((size_t)bh * 32 + s) * 128 + t] = s0;
    }
}

// ---------- K6: reduce context partials ----------
__global__ __launch_bounds__(128) void ctx_reduce_kernel(
        const float* __restrict__ pctx, float* __restrict__ out) {
    const int bh = blockIdx.x;
    const int t = threadIdx.x;
    float acc = 0.f;
    for (int s2 = 0; s2 < 32; ++s2) acc += pctx[((size_t)bh * 32 + s2) * 128 + t];
    out[(size_t)bh * 128 + t] = acc;
}

extern "C" void kernel_launch(void* const* d_in, const int* in_sizes, int n_in,
                              void* d_out, int out_size, void* d_ws, size_t ws_size,
                              hipStream_t stream) {
    const float* query   = (const float*)d_in[0];
    const float* key_in  = (const float*)d_in[1];
    const float* value   = (const float*)d_in[2];
    const float* pa      = (const float*)d_in[3];
    const float* conv_w  = (const float*)d_in[4];
    const float* conv_b  = (const float*)d_in[5];
    const float* w_u     = (const float*)d_in[6];
    const float* w_q     = (const float*)d_in[7];
    const float* w_v     = (const float*)d_in[8];
    const float* bias    = (const float*)d_in[9];
    const float* score_w = (const float*)d_in[10];
    const float* score_b = (const float*)d_in[11];

    float* out = (float*)d_out;
    float* ctx_out = out;                 // [128,128]
    float* align_out = out + 16384;       // [16,8,4096]

    char* ws = (char*)d_ws;
    const size_t OFF_Q    = 0;                        // 64 KB
    const size_t OFF_LOC  = 65536;                    // 2.62 MB
    const size_t OFF_WVT  = OFF_LOC + 2621440;        // 2 MB (tiled bf16)
    const size_t OFF_PCTX = OFF_WVT + 2097152;        // 2 MB
    const size_t OFF_LE   = OFF_PCTX + 2097152;       // 33.55 MB
    const size_t OFF_KBF  = OFF_LE + 33554432;        // 128 MB (tiled bf16)

    float* ws_q            = (float*)(ws + OFF_Q);
    float* ws_loc          = (float*)(ws + OFF_LOC);
    unsigned short* ws_wvT = (unsigned short*)(ws + OFF_WVT);
    float* ws_pctx         = (float*)(ws + OFF_PCTX);
    float* ws_le           = (float*)(ws + OFF_LE);
    unsigned short* ws_kbf = (unsigned short*)(ws + OFF_KBF);

    hipLaunchKernelGGL(wv_tile_kernel, dim3(8, 16), dim3(256), 0, stream, w_v, ws_wvT);
    hipLaunchKernelGGL(qproj_kernel, dim3(16), dim3(1024), 0, stream, query, w_q, ws_q);
    hipLaunchKernelGGL(loc_conv_kernel, dim3(16, 16), dim3(256), 0, stream, pa, conv_w, conv_b, ws_loc);
    hipLaunchKernelGGL(loc_energy_kernel, dim3(16, 32), dim3(256), 0, stream, ws_loc, w_u, ws_le);
    hipLaunchKernelGGL(key_tile_kernel, dim3(256, 16), dim3(512), 0, stream, key_in, ws_kbf);
    hipLaunchKernelGGL(gemm_score_kernel, dim3(1024), dim3(512), 0, stream,
                       ws_kbf, ws_wvT, ws_le, ws_q, bias, score_w, score_b, align_out);
    hipLaunchKernelGGL(softmax_kernel, dim3(128), dim3(256), 0, stream, align_out);
    hipLaunchKernelGGL(ctx_partial_kernel, dim3(32, 128), dim3(256), 0, stream, value, align_out, ws_pctx);
    hipLaunchKernelGGL(ctx_reduce_kernel, dim3(128), dim3(128), 0, stream, ws_pctx, ctx_out);
}

// Round 14
// 382.874 us; speedup vs baseline: 1.1291x; 1.1291x over previous
//
#include <hip/hip_runtime.h>
#include <hip/hip_bf16.h>
#include <cstdint>

typedef __attribute__((ext_vector_type(8))) short bf16x8;
typedef __attribute__((ext_vector_type(4))) float f32x4;
typedef __attribute__((ext_vector_type(8))) unsigned short u16x8;
typedef __attribute__((ext_vector_type(4))) unsigned int u32x4;

__device__ __forceinline__ unsigned short f2bf(float f) {
    unsigned int u = __float_as_uint(f);
    unsigned int r = (u + 0x7fffu + ((u >> 16) & 1u)) >> 16;
    return (unsigned short)r;
}

__device__ __forceinline__ float tanh_fast(float x) {
    return 1.0f - 2.0f / (__expf(2.0f * x) + 1.0f);
}

#define GLDS(SRC, DST) __builtin_amdgcn_global_load_lds(                         \
        (const __attribute__((address_space(1))) void*)(SRC),                    \
        (__attribute__((address_space(3))) void*)(DST), 16, 0, 0)

// ---------- K0: w_v -> bf16 tiled B for BK=64 ----------
// per (hp, kt): 2048 chunks; chunk = kh*1024 + hfB*512 + cbg*64 + lane
// holds col e = hp*256+hfB*128+cbg*16+(lane&15), k f = kt*64+kh*32+(lane>>4)*8
__global__ __launch_bounds__(256) void wv_tile_kernel(
        const float* __restrict__ wv, unsigned short* __restrict__ out) {
    __shared__ float tile[64][130];
    const int h = blockIdx.x;    // 0..7
    const int kt = blockIdx.y;   // 0..15
    const int hp = h >> 1, hfB = h & 1;
    const int t = threadIdx.x;
    for (int i = t; i < 2048; i += 256) {           // 64 f x 32 float4
        const int f = i >> 5, e4 = (i & 31) * 4;
        const float4 v = *reinterpret_cast<const float4*>(
            wv + (size_t)(kt * 64 + f) * 1024 + hp * 256 + hfB * 128 + e4);
        tile[f][e4 + 0] = v.x; tile[f][e4 + 1] = v.y;
        tile[f][e4 + 2] = v.z; tile[f][e4 + 3] = v.w;
    }
    __syncthreads();
#pragma unroll
    for (int cc = 0; cc < 4; ++cc) {
        const int c = cc * 256 + t;                 // 0..1023
        const int kh = c >> 9, cbg = (c >> 6) & 7, lane = c & 63;
        u16x8 u;
#pragma unroll
        for (int jj = 0; jj < 8; ++jj)
            u[jj] = f2bf(tile[kh * 32 + (lane >> 4) * 8 + jj][cbg * 16 + (lane & 15)]);
        *reinterpret_cast<u16x8*>(out + ((size_t)(hp * 16 + kt) * 2048
                                         + kh * 1024 + hfB * 512 + cbg * 64 + lane) * 8) = u;
    }
}

// ---------- K1: q projection ----------
__global__ __launch_bounds__(1024) void qproj_kernel(
        const float* __restrict__ query, const float* __restrict__ w_q,
        float* __restrict__ ws_q) {
    __shared__ float qs[1024];
    const int b = blockIdx.x;
    const int t = threadIdx.x;
    qs[t] = query[(size_t)b * 1024 + t];
    __syncthreads();
    float acc = 0.f;
    const float* w = w_q + t;
#pragma unroll 8
    for (int f = 0; f < 1024; ++f) acc = fmaf(qs[f], w[(size_t)f * 1024], acc);
    ws_q[(size_t)b * 1024 + t] = acc;
}

// ---------- K2: fused conv1d + location-energy ----------
// le[b,k,d] = tanh(sum_c conv(pa)[b,c,k] * w_u[c,d])
__global__ __launch_bounds__(256) void loc_le_kernel(
        const float* __restrict__ pa, const float* __restrict__ conv_w,
        const float* __restrict__ conv_b, const float* __restrict__ w_u,
        float* __restrict__ le) {
    __shared__ float pas[8][132];      // k0-1 .. k0+128
    __shared__ float wu_s[10][128];
    __shared__ float cw[240];
    __shared__ float cb[16];
    const int b = blockIdx.x, k0 = blockIdx.y * 128;
    const int t = threadIdx.x;
    for (int i = t; i < 8 * 130; i += 256) {
        const int hh = i / 130, kk = i % 130;
        const int gk = k0 + kk - 1;
        pas[hh][kk] = (gk >= 0 && gk < 4096) ? pa[((size_t)(b * 8 + hh)) * 4096 + gk] : 0.f;
    }
    for (int i = t; i < 1280; i += 256) wu_s[i >> 7][i & 127] = w_u[i];
    if (t < 240) cw[t] = conv_w[t];
    if (t < 10) cb[t] = conv_b[t];
    __syncthreads();
    const int k = t >> 1;
    const int d0 = (t & 1) * 64;
    float lc[10];
#pragma unroll
    for (int c = 0; c < 10; ++c) {
        float acc = cb[c];
#pragma unroll
        for (int hh = 0; hh < 8; ++hh) {
            acc += pas[hh][k] * cw[(c * 8 + hh) * 3 + 0]
                 + pas[hh][k + 1] * cw[(c * 8 + hh) * 3 + 1]
                 + pas[hh][k + 2] * cw[(c * 8 + hh) * 3 + 2];
        }
        lc[c] = acc;
    }
    float* dst = le + ((size_t)(b * 4096) + k0 + k) * 128 + d0;
#pragma unroll
    for (int dd = 0; dd < 64; dd += 4) {
        float4 o;
#pragma unroll
        for (int jj = 0; jj < 4; ++jj) {
            float s = 0.f;
#pragma unroll
            for (int c = 0; c < 10; ++c) s += lc[c] * wu_s[c][d0 + dd + jj];
            ((float*)&o)[jj] = tanh_fast(s);
        }
        *reinterpret_cast<float4*>(dst + dd) = o;
    }
}

// ---------- K3: counted-vmcnt pipelined GEMM, fused A-convert + score ----------
// BM=256, BN=256 (2 heads), BK=64; 512 thr, 8 waves (2M x 4N), wave 128x64.
// A: fp32 global (coalesced 128B/4lanes) -> regs -> cvt_pk -> XOR-swizzled
//    ds_write; consumed one kt later. B: pre-tiled bf16 via GLDS, certified by
//    vmcnt(12) once per kt. No vmem drains in the loop; lgkmcnt(0) only.
#define NKT 16
__global__ __launch_bounds__(512) void gemm_score_kernel(
        const float* __restrict__ key_in, const unsigned short* __restrict__ wvT,
        const float* __restrict__ le,
        const float* __restrict__ ws_q, const float* __restrict__ bias,
        const float* __restrict__ score_w, const float* __restrict__ score_b,
        float* __restrict__ align_out) {
    __shared__ __align__(16) unsigned short As[2][16384];   // 64 KB
    __shared__ __align__(16) unsigned short Bs[2][16384];   // 64 KB
    __shared__ float qb_sm[256], sw_sm[128];
    __shared__ float partial[256][4];

    const int t = threadIdx.x;
    const int lane = t & 63, wid = t >> 6;
    const int wm = wid >> 2;          // 0..1 : 128-row half
    const int wn = wid & 3;           // 0..3 : (head, d-half)

    // XCD swizzle: 4 head-pair blocks of one 256-row panel adjacent on one XCD
    const int fid = blockIdx.x;       // 0..1023
    const int x = fid & 7, j = fid >> 3;
    const int bm = x * 32 + (j >> 2);        // panel 0..255
    const int hp = j & 3;
    const int b = bm >> 4;
    const int kk0 = (bm & 15) << 8;

    if (t < 256) {
        const int hh = t >> 7, d = t & 127;
        qb_sm[t] = ws_q[(size_t)(b * 8 + hp * 2 + hh) * 128 + d] + bias[d];
        if (t < 128) sw_sm[t] = score_w[t];
    }

    // ---- A staging geometry: thread covers rows {rA, rA+128}, kseg ksA (8 floats)
    const int rA = t >> 2, ksA = t & 3;
    const float* aBase = key_in + ((size_t)(b * 4096 + kk0) + rA) * 1024 + ksA * 8;
    const int mfg64 = ((rA >> 4) & 7) * 64 + ksA * 16;
    const int r15x = (rA & 15) ^ (ksA << 1);
    const int cK0 = mfg64 + r15x;                 // kh=0 chunk (hf0)
    const int cK1 = 1024 + mfg64 + (r15x ^ 4);    // kh=1 chunk (hf0)

    // fragment-read lane mapping (same involution)
    const int kg4R = lane >> 4;
    const int laneA0 = kg4R * 16 + ((lane & 15) ^ (kg4R << 1));
    const int laneA1 = kg4R * 16 + ((lane & 15) ^ (kg4R << 1) ^ 4);

    const unsigned short* bT = wvT + (size_t)(hp * 16) * 16384;

    float4 st0, st1, st2, st3, st4, st5, st6, st7;

#define LOADA(KT) {                                                               \
        const float* p_ = aBase + (size_t)(KT) * 64;                              \
        st0 = *reinterpret_cast<const float4*>(p_);                               \
        st1 = *reinterpret_cast<const float4*>(p_ + 4);                           \
        st2 = *reinterpret_cast<const float4*>(p_ + 32);                          \
        st3 = *reinterpret_cast<const float4*>(p_ + 36);                          \
        st4 = *reinterpret_cast<const float4*>(p_ + 131072);                      \
        st5 = *reinterpret_cast<const float4*>(p_ + 131076);                      \
        st6 = *reinterpret_cast<const float4*>(p_ + 131104);                      \
        st7 = *reinterpret_cast<const float4*>(p_ + 131108); }

#define CVT4(dst_, a_, b_) {                                                      \
        __hip_bfloat162 x0_ = __float22bfloat162_rn({a_.x, a_.y});                \
        __hip_bfloat162 x1_ = __float22bfloat162_rn({a_.z, a_.w});                \
        __hip_bfloat162 x2_ = __float22bfloat162_rn({b_.x, b_.y});                \
        __hip_bfloat162 x3_ = __float22bfloat162_rn({b_.z, b_.w});                \
        dst_[0] = *reinterpret_cast<unsigned int*>(&x0_);                         \
        dst_[1] = *reinterpret_cast<unsigned int*>(&x1_);                         \
        dst_[2] = *reinterpret_cast<unsigned int*>(&x2_);                         \
        dst_[3] = *reinterpret_cast<unsigned int*>(&x3_); }

#define WRITEA(BUF) {                                                             \
        u32x4 u0_, u1_, u2_, u3_;                                                 \
        CVT4(u0_, st0, st1); CVT4(u1_, st2, st3);                                 \
        CVT4(u2_, st4, st5); CVT4(u3_, st6, st7);                                 \
        *reinterpret_cast<u32x4*>(&As[BUF][cK0 * 8]) = u0_;                       \
        *reinterpret_cast<u32x4*>(&As[BUF][cK1 * 8]) = u1_;                       \
        *reinterpret_cast<u32x4*>(&As[BUF][(512 + cK0) * 8]) = u2_;               \
        *reinterpret_cast<u32x4*>(&As[BUF][(512 + cK1) * 8]) = u3_; }

#define SBALL(BUF, KT) {                                                          \
        const unsigned short* s_ = bT + (size_t)(KT) * 16384;                     \
        GLDS(s_ + t * 8, &Bs[BUF][t * 8]);                                        \
        GLDS(s_ + 4096 + t * 8, &Bs[BUF][4096 + t * 8]);                          \
        GLDS(s_ + 8192 + t * 8, &Bs[BUF][8192 + t * 8]);                          \
        GLDS(s_ + 12288 + t * 8, &Bs[BUF][12288 + t * 8]); }

    f32x4 acc[8][4] = {};

    // prologue: A0, B0, write A0, preload A1
    LOADA(0);
    SBALL(0, 0);
    WRITEA(0);
    LOADA(1);

    for (int kt = 0; kt < NKT; ++kt) {
        const int cur = kt & 1, nxt = cur ^ 1;
        WRITEA(nxt);                         // A(kt+1) from regs
        LOADA((kt + 2) & (NKT - 1));         // A(kt+2) -> regs
        SBALL(nxt, (kt + 1) & (NKT - 1));    // B(kt+1)
        // certify my B(cur) (4 oldest of 16); flush my ds_writes; sync all waves
        asm volatile("s_waitcnt vmcnt(12)\n\ts_waitcnt lgkmcnt(0)\n\ts_barrier" ::: "memory");

        bf16x8 bg[4], af[4];
#pragma unroll
        for (int kh = 0; kh < 2; ++kh) {
            const int lA = kh ? laneA1 : laneA0;
            const int aOff = kh * 1024 + wm * 512;
            const int bOff = kh * 1024 + (wn >> 1) * 512;
#pragma unroll
            for (int nf = 0; nf < 4; ++nf)
                bg[nf] = *reinterpret_cast<const bf16x8*>(
                    &Bs[cur][(bOff + ((wn & 1) * 4 + nf) * 64 + lane) * 8]);
#pragma unroll
            for (int mf = 0; mf < 4; ++mf)
                af[mf] = *reinterpret_cast<const bf16x8*>(
                    &As[cur][(aOff + mf * 64 + lA) * 8]);
            __builtin_amdgcn_s_setprio(1);
#pragma unroll
            for (int mf = 0; mf < 4; ++mf)
#pragma unroll
                for (int nf = 0; nf < 4; ++nf)
                    acc[mf][nf] = __builtin_amdgcn_mfma_f32_16x16x32_bf16(
                        af[mf], bg[nf], acc[mf][nf], 0, 0, 0);
            __builtin_amdgcn_s_setprio(0);
#pragma unroll
            for (int mf = 0; mf < 4; ++mf)
                af[mf] = *reinterpret_cast<const bf16x8*>(
                    &As[cur][(aOff + (4 + mf) * 64 + lA) * 8]);
            __builtin_amdgcn_s_setprio(1);
#pragma unroll
            for (int mf = 0; mf < 4; ++mf)
#pragma unroll
                for (int nf = 0; nf < 4; ++nf)
                    acc[4 + mf][nf] = __builtin_amdgcn_mfma_f32_16x16x32_bf16(
                        af[mf], bg[nf], acc[4 + mf][nf], 0, 0, 0);
            __builtin_amdgcn_s_setprio(0);
        }
        // end-of-kt: reads consumed (MFMA lgkm deps); next kt's writes wait here
        asm volatile("s_barrier" ::: "memory");
    }

    // ---- epilogue: score = sum_d tanh(kproj + q + bias + le) * sw ----
    const float K2 = 2.8853900817779268f;
    const float sb = score_b[0];
    const int g = lane >> 4;
    const int l15 = lane & 15;
    float kqb[4], swv[4];
#pragma unroll
    for (int nf = 0; nf < 4; ++nf) {
        const int d128 = (wn & 1) * 64 + nf * 16 + l15;
        kqb[nf] = qb_sm[(wn >> 1) * 128 + d128] * K2;
        swv[nf] = sw_sm[d128];
    }
    const float* leB = le + ((size_t)(b * 4096 + kk0) + wm * 128 + g * 4) * 128
                       + (wn & 1) * 64 + l15;

#pragma unroll
    for (int mf = 0; mf < 8; ++mf) {
        float lv[16];
#pragma unroll
        for (int jj = 0; jj < 4; ++jj)
#pragma unroll
            for (int nf = 0; nf < 4; ++nf)
                lv[jj * 4 + nf] = leB[(size_t)(mf * 16 + jj) * 128 + nf * 16];
#pragma unroll
        for (int jj = 0; jj < 4; ++jj) {
            const int row_l = wm * 128 + mf * 16 + g * 4 + jj;
            float sum = 0.f;
#pragma unroll
            for (int nf = 0; nf < 4; ++nf) {
                const float m = fmaf(K2, lv[jj * 4 + nf], kqb[nf]);
                const float tt = fmaf(K2, acc[mf][nf][jj], m);
                const float y = __builtin_amdgcn_exp2f(tt);
                const float r = fmaf(-2.0f, __builtin_amdgcn_rcpf(y + 1.0f), 1.0f);
                sum = fmaf(r, swv[nf], sum);
            }
            sum += __shfl_xor(sum, 1);
            sum += __shfl_xor(sum, 2);
            sum += __shfl_xor(sum, 4);
            sum += __shfl_xor(sum, 8);
            if (l15 == 0) partial[row_l][wn] = sum;
        }
    }
    __syncthreads();
    if (t < 512) {
        const int r = t >> 1, hh = t & 1;
        const float sc = partial[r][hh * 2] + partial[r][hh * 2 + 1] + sb;
        align_out[(size_t)(b * 8 + hp * 2 + hh) * 4096 + kk0 + r] = sc;
    }
}

// ---------- K4: softmax over k ----------
__global__ __launch_bounds__(256) void softmax_kernel(float* __restrict__ align_o) {
    const int bh = blockIdx.x;
    float* row = align_o + (size_t)bh * 4096;
    const int t = threadIdx.x;
    float v[16];
    float m = -1e30f;
#pragma unroll
    for (int i = 0; i < 16; ++i) {
        v[i] = row[i * 256 + t];
        m = fmaxf(m, v[i]);
    }
#pragma unroll
    for (int off = 32; off; off >>= 1) m = fmaxf(m, __shfl_xor(m, off));
    __shared__ float sm[4], ss[4];
    const int wid = t >> 6;
    if ((t & 63) == 0) sm[wid] = m;
    __syncthreads();
    m = fmaxf(fmaxf(sm[0], sm[1]), fmaxf(sm[2], sm[3]));
    float s = 0.f;
#pragma unroll
    for (int i = 0; i < 16; ++i) {
        v[i] = __expf(v[i] - m);
        s += v[i];
    }
#pragma unroll
    for (int off = 32; off; off >>= 1) s += __shfl_xor(s, off);
    if ((t & 63) == 0) ss[wid] = s;
    __syncthreads();
    s = ss[0] + ss[1] + ss[2] + ss[3];
    const float inv = 1.f / s;
#pragma unroll
    for (int i = 0; i < 16; ++i) row[i * 256 + t] = v[i] * inv;
}

// ---------- K5: split-K context partials ----------
__global__ __launch_bounds__(256) void ctx_partial_kernel(
        const float* __restrict__ value, const float* __restrict__ align_o,
        float* __restrict__ pctx) {
    const int s = blockIdx.x;    // 0..31
    const int bh = blockIdx.y;   // 0..127
    const int b = bh >> 3, h = bh & 7;
    const int t = threadIdx.x;
    const int d4 = (t & 31) * 4;
    const int kg = t >> 5;
    const float* arow = align_o + (size_t)bh * 4096 + s * 128;
    const float* vbase = value + ((size_t)(b * 4096 + s * 128)) * 1024 + h * 128 + d4;
    float4 acc = {0.f, 0.f, 0.f, 0.f};
    for (int i = 0; i < 16; ++i) {
        const int kk = i * 8 + kg;
        const float a = arow[kk];
        const float4 v = *reinterpret_cast<const float4*>(vbase + (size_t)kk * 1024);
        acc.x += a * v.x; acc.y += a * v.y; acc.z += a * v.z; acc.w += a * v.w;
    }
    __shared__ float sm2[8][128];
    *reinterpret_cast<float4*>(&sm2[kg][d4]) = acc;
    __syncthreads();
    if (t < 128) {
        float s0 = 0.f;
#pragma unroll
        for (int gg = 0; gg < 8; ++gg) s0 += sm2[gg][t];
        pctx[((size_t)bh * 32 + s) * 128 + t] = s0;
    }
}

// ---------- K6: reduce context partials ----------
__global__ __launch_bounds__(128) void ctx_reduce_kernel(
        const float* __restrict__ pctx, float* __restrict__ out) {
    const int bh = blockIdx.x;
    const int t = threadIdx.x;
    float acc = 0.f;
    for (int s2 = 0; s2 < 32; ++s2) acc += pctx[((size_t)bh * 32 + s2) * 128 + t];
    out[(size_t)bh * 128 + t] = acc;
}

extern "C" void kernel_launch(void* const* d_in, const int* in_sizes, int n_in,
                              void* d_out, int out_size, void* d_ws, size_t ws_size,
                              hipStream_t stream) {
    const float* query   = (const float*)d_in[0];
    const float* key_in  = (const float*)d_in[1];
    const float* value   = (const float*)d_in[2];
    const float* pa      = (const float*)d_in[3];
    const float* conv_w  = (const float*)d_in[4];
    const float* conv_b  = (const float*)d_in[5];
    const float* w_u     = (const float*)d_in[6];
    const float* w_q     = (const float*)d_in[7];
    const float* w_v     = (const float*)d_in[8];
    const float* bias    = (const float*)d_in[9];
    const float* score_w = (const float*)d_in[10];
    const float* score_b = (const float*)d_in[11];

    float* out = (float*)d_out;
    float* ctx_out = out;                 // [128,128]
    float* align_out = out + 16384;       // [16,8,4096]

    char* ws = (char*)d_ws;
    const size_t OFF_Q    = 0;                        // 64 KB
    const size_t OFF_WVT  = 65536;                    // 2 MB (tiled bf16)
    const size_t OFF_PCTX = OFF_WVT + 2097152;        // 2 MB
    const size_t OFF_LE   = OFF_PCTX + 2097152;       // 33.55 MB

    float* ws_q            = (float*)(ws + OFF_Q);
    unsigned short* ws_wvT = (unsigned short*)(ws + OFF_WVT);
    float* ws_pctx         = (float*)(ws + OFF_PCTX);
    float* ws_le           = (float*)(ws + OFF_LE);

    hipLaunchKernelGGL(wv_tile_kernel, dim3(8, 16), dim3(256), 0, stream, w_v, ws_wvT);
    hipLaunchKernelGGL(qproj_kernel, dim3(16), dim3(1024), 0, stream, query, w_q, ws_q);
    hipLaunchKernelGGL(loc_le_kernel, dim3(16, 32), dim3(256), 0, stream,
                       pa, conv_w, conv_b, w_u, ws_le);
    hipLaunchKernelGGL(gemm_score_kernel, dim3(1024), dim3(512), 0, stream,
                       key_in, ws_wvT, ws_le, ws_q, bias, score_w, score_b, align_out);
    hipLaunchKernelGGL(softmax_kernel, dim3(128), dim3(256), 0, stream, align_out);
    hipLaunchKernelGGL(ctx_partial_kernel, dim3(32, 128), dim3(256), 0, stream, value, align_out, ws_pctx);
    hipLaunchKernelGGL(ctx_reduce_kernel, dim3(128), dim3(128), 0, stream, ws_pctx, ctx_out);
}

// Round 15
// 345.025 us; speedup vs baseline: 1.2530x; 1.1097x over previous
//
#include <hip/hip_runtime.h>
#include <hip/hip_bf16.h>
#include <cstdint>

typedef __attribute__((ext_vector_type(8))) short bf16x8;
typedef __attribute__((ext_vector_type(4))) float f32x4;
typedef __attribute__((ext_vector_type(8))) unsigned short u16x8;
typedef __attribute__((ext_vector_type(4))) unsigned int u32x4;

__device__ __forceinline__ unsigned short f2bf(float f) {
    unsigned int u = __float_as_uint(f);
    unsigned int r = (u + 0x7fffu + ((u >> 16) & 1u)) >> 16;
    return (unsigned short)r;
}

__device__ __forceinline__ float tanh_fast(float x) {
    return 1.0f - 2.0f / (__expf(2.0f * x) + 1.0f);
}

#define GLDS(SRC, DST) __builtin_amdgcn_global_load_lds(                         \
        (const __attribute__((address_space(1))) void*)(SRC),                    \
        (__attribute__((address_space(3))) void*)(DST), 16, 0, 0)

// ---------- K0: w_v -> bf16 fragment-tiled B (per head, BK=32 layout) ----------
__global__ __launch_bounds__(256) void wv_tile_kernel(
        const float* __restrict__ wv, unsigned short* __restrict__ out) {
    __shared__ float tile[32][129];
    const int h = blockIdx.x;    // 0..7
    const int kt = blockIdx.y;   // 0..31
    const int t = threadIdx.x;
    for (int i = t; i < 1024; i += 256) {
        const int fl = i >> 5;
        const int e4 = (i & 31) * 4;
        const float4 v = *reinterpret_cast<const float4*>(
            wv + (size_t)(kt * 32 + fl) * 1024 + h * 128 + e4);
        tile[fl][e4 + 0] = v.x; tile[fl][e4 + 1] = v.y;
        tile[fl][e4 + 2] = v.z; tile[fl][e4 + 3] = v.w;
    }
    __syncthreads();
#pragma unroll
    for (int cc2 = 0; cc2 < 2; ++cc2) {
        const int c = cc2 * 256 + t;
        const int cb = c >> 6, kg = (c >> 4) & 3, ccl = c & 15;
        const int e_local = cb * 16 + ccl;
        u16x8 u;
#pragma unroll
        for (int jj = 0; jj < 8; ++jj) u[jj] = f2bf(tile[kg * 8 + jj][e_local]);
        *reinterpret_cast<u16x8*>(out + (((size_t)h * 32 + kt) * 512 + c) * 8) = u;
    }
}

// ---------- K1: q projection (coalesced: one col per thread) ----------
__global__ __launch_bounds__(1024) void qproj_kernel(
        const float* __restrict__ query, const float* __restrict__ w_q,
        float* __restrict__ ws_q) {
    __shared__ float qs[1024];
    const int b = blockIdx.x;
    const int t = threadIdx.x;
    qs[t] = query[(size_t)b * 1024 + t];
    __syncthreads();
    float acc = 0.f;
    const float* w = w_q + t;
#pragma unroll 8
    for (int f = 0; f < 1024; ++f) acc = fmaf(qs[f], w[(size_t)f * 1024], acc);
    ws_q[(size_t)b * 1024 + t] = acc;
}

// ---------- K2: fused conv1d + location-energy ----------
__global__ __launch_bounds__(256) void loc_le_kernel(
        const float* __restrict__ pa, const float* __restrict__ conv_w,
        const float* __restrict__ conv_b, const float* __restrict__ w_u,
        float* __restrict__ le) {
    __shared__ float pas[8][132];
    __shared__ float wu_s[10][128];
    __shared__ float cw[240];
    __shared__ float cb[16];
    const int b = blockIdx.x, k0 = blockIdx.y * 128;
    const int t = threadIdx.x;
    for (int i = t; i < 8 * 130; i += 256) {
        const int hh = i / 130, kk = i % 130;
        const int gk = k0 + kk - 1;
        pas[hh][kk] = (gk >= 0 && gk < 4096) ? pa[((size_t)(b * 8 + hh)) * 4096 + gk] : 0.f;
    }
    for (int i = t; i < 1280; i += 256) wu_s[i >> 7][i & 127] = w_u[i];
    if (t < 240) cw[t] = conv_w[t];
    if (t < 10) cb[t] = conv_b[t];
    __syncthreads();
    const int k = t >> 1;
    const int d0 = (t & 1) * 64;
    float lc[10];
#pragma unroll
    for (int c = 0; c < 10; ++c) {
        float acc = cb[c];
#pragma unroll
        for (int hh = 0; hh < 8; ++hh) {
            acc += pas[hh][k] * cw[(c * 8 + hh) * 3 + 0]
                 + pas[hh][k + 1] * cw[(c * 8 + hh) * 3 + 1]
                 + pas[hh][k + 2] * cw[(c * 8 + hh) * 3 + 2];
        }
        lc[c] = acc;
    }
    float* dst = le + ((size_t)(b * 4096) + k0 + k) * 128 + d0;
#pragma unroll
    for (int dd = 0; dd < 64; dd += 4) {
        float4 o;
#pragma unroll
        for (int jj = 0; jj < 4; ++jj) {
            float s = 0.f;
#pragma unroll
            for (int c = 0; c < 10; ++c) s += lc[c] * wu_s[c][d0 + dd + jj];
            ((float*)&o)[jj] = tanh_fast(s);
        }
        *reinterpret_cast<float4*>(dst + dd) = o;
    }
}

// ---------- K3: r10 GEMM + counted-vmcnt sync (T3+T4+T5) ----------
// BM=128, BN=256 (2 heads), BK=32; 512 thr, 8 waves (2M x 4N), wave 64x64.
// A: fp32 coalesced -> regs -> cvt_pk -> XOR-swizzled ds_write.
// B: pre-tiled bf16 via GLDS. Per kt: cert = vmcnt(4)+lgkmcnt(0)+barrier
// (B(nxt)+A(kt+2) stay in flight through MFMA); end = bare s_barrier.
#define NT 32
__global__ __launch_bounds__(512) void gemm_score_kernel(
        const float* __restrict__ key_in, const unsigned short* __restrict__ wvT_tiled,
        const float* __restrict__ le,
        const float* __restrict__ ws_q, const float* __restrict__ bias,
        const float* __restrict__ score_w, const float* __restrict__ score_b,
        float* __restrict__ align_out) {
    __shared__ __align__(16) unsigned short As[2][4096];    // 16 KB
    __shared__ __align__(16) unsigned short Bs[2][8192];    // 32 KB
    __shared__ float qb_sm[256], sw_sm[128];
    __shared__ float partial[128][4];

    const int t = threadIdx.x;
    const int lane = t & 63, wid = t >> 6;
    const int wm = wid >> 2;          // 0..1 : M-half
    const int wn = wid & 3;           // 0..3 : (head, d-half)

    // XCD swizzle: the 4 head-pair blocks of one panel adjacent on one XCD
    const int fid = blockIdx.x;       // 0..2047
    const int x = fid & 7, j = fid >> 3;     // j: 0..255
    const int bm = x * 64 + (j >> 2);        // panel 0..511 (128 rows)
    const int hp = j & 3;                    // head-pair 0..3
    const int b = bm >> 5;
    const int kk0 = (bm & 31) << 7;

    if (t < 256) {
        const int hh = t >> 7, d = t & 127;
        qb_sm[t] = ws_q[(size_t)(b * 8 + hp * 2 + hh) * 128 + d] + bias[d];
        if (t < 128) sw_sm[t] = score_w[t];
    }

    // ---- A staging: thread t reads row r_=t>>2, kseg ks=t&3 (coalesced 128B/4 lanes)
    const int r_ = t >> 2, ks = t & 3;
    const float* aRow = key_in + ((size_t)(b * 4096 + kk0) + r_) * 1024 + ks * 8;
    const int cW = (t >> 6) * 64 + ks * 16 + (r_ & 15);
    const int dst0 = (cW ^ (ks | ((ks & 1) << 2))) * 8;            // ushort idx

    // fragment-read lane swizzle (same involution): kg = lane>>4
    const int kgR = lane >> 4;
    const int laneSwz = lane ^ (kgR | ((kgR & 1) << 2));

    // ---- B staging: thread stages two 16B chunks of one head ----
    const unsigned short* bT = wvT_tiled
        + (size_t)(hp * 2 + (t >> 8)) * 131072 + (t & 255) * 8;
    const int dstB = (t >> 8) * 4096 + (t & 255) * 8;              // ushort idx

    float4 st0, st1;

#define LOADA(KT) {                                                               \
        const float* p_ = aRow + (KT) * 32;                                       \
        st0 = *reinterpret_cast<const float4*>(p_);                               \
        st1 = *reinterpret_cast<const float4*>(p_ + 4); }

#define WRITEA(BUF) {                                                             \
        __hip_bfloat162 h0_ = __float22bfloat162_rn({st0.x, st0.y});              \
        __hip_bfloat162 h1_ = __float22bfloat162_rn({st0.z, st0.w});              \
        __hip_bfloat162 h2_ = __float22bfloat162_rn({st1.x, st1.y});              \
        __hip_bfloat162 h3_ = __float22bfloat162_rn({st1.z, st1.w});              \
        u32x4 u_;                                                                 \
        u_[0] = *reinterpret_cast<unsigned int*>(&h0_);                           \
        u_[1] = *reinterpret_cast<unsigned int*>(&h1_);                           \
        u_[2] = *reinterpret_cast<unsigned int*>(&h2_);                           \
        u_[3] = *reinterpret_cast<unsigned int*>(&h3_);                           \
        *reinterpret_cast<u32x4*>(&As[BUF][dst0]) = u_; }

#define STAGE_B(BUF, KT) {                                                        \
        GLDS(bT + (size_t)(KT) * 4096, &Bs[BUF][dstB]);                           \
        GLDS(bT + (size_t)(KT) * 4096 + 2048, &Bs[BUF][dstB + 2048]); }

    f32x4 acc[4][4] = {};

    // prologue: B(0)->buf0, A(0)->buf0 (regs->LDS), preload A(1) regs
    LOADA(0);
    STAGE_B(0, 0);
    WRITEA(0);
    LOADA(1);

    for (int kt = 0; kt < NT; ++kt) {
        const int cur = kt & 1, nxt = cur ^ 1;
        STAGE_B(nxt, (kt + 1) & (NT - 1));   // wraps harmlessly on last iter
        WRITEA(nxt);                          // regs of A(kt+1); implicit vmcnt wait
        LOADA((kt + 2) & (NT - 1));
        // certify B(cur) (2 oldest of 6); flush my A ds_writes; sync
        asm volatile("s_waitcnt vmcnt(4)\n\t"
                     "s_waitcnt lgkmcnt(0)\n\t"
                     "s_barrier" ::: "memory");

        bf16x8 af[4], bg[4];
#pragma unroll
        for (int mf = 0; mf < 4; ++mf)
            af[mf] = *reinterpret_cast<const bf16x8*>(
                &As[cur][((wm * 4 + mf) * 64 + laneSwz) * 8]);
#pragma unroll
        for (int nf = 0; nf < 4; ++nf)
            bg[nf] = *reinterpret_cast<const bf16x8*>(
                &Bs[cur][(wn >> 1) * 4096 + ((wn & 1) * 4 + nf) * 512 + lane * 8]);
        __builtin_amdgcn_s_setprio(1);
#pragma unroll
        for (int mf = 0; mf < 4; ++mf)
#pragma unroll
            for (int nf = 0; nf < 4; ++nf)
                acc[mf][nf] = __builtin_amdgcn_mfma_f32_16x16x32_bf16(
                    af[mf], bg[nf], acc[mf][nf], 0, 0, 0);
        __builtin_amdgcn_s_setprio(0);
        // end-of-kt: my ds_reads done (lgkm deps before MFMA use); fence rewrites
        asm volatile("s_barrier" ::: "memory");
    }

    // ---- epilogue: score = sum_d tanh(kproj + q + bias + le) * sw ----
    const float K2 = 2.8853900817779268f;
    const float sb = score_b[0];
    const int g = lane >> 4;
    const int l15 = lane & 15;
    float kqb[4], swv[4];
#pragma unroll
    for (int nf = 0; nf < 4; ++nf) {
        const int d128 = (wn & 1) * 64 + nf * 16 + l15;
        kqb[nf] = qb_sm[(wn >> 1) * 128 + d128] * K2;
        swv[nf] = sw_sm[d128];
    }
    const float* leB = le + ((size_t)(b * 4096 + kk0) + wm * 64 + g * 4) * 128
                       + (wn & 1) * 64 + l15;

#pragma unroll
    for (int mf = 0; mf < 4; ++mf) {
        float lv[16];
#pragma unroll
        for (int jj = 0; jj < 4; ++jj)
#pragma unroll
            for (int nf = 0; nf < 4; ++nf)
                lv[jj * 4 + nf] = leB[(size_t)(mf * 16 + jj) * 128 + nf * 16];
#pragma unroll
        for (int jj = 0; jj < 4; ++jj) {
            const int row_l = wm * 64 + mf * 16 + g * 4 + jj;
            float sum = 0.f;
#pragma unroll
            for (int nf = 0; nf < 4; ++nf) {
                const float m = fmaf(K2, lv[jj * 4 + nf], kqb[nf]);
                const float tt = fmaf(K2, acc[mf][nf][jj], m);
                const float y = __builtin_amdgcn_exp2f(tt);
                const float r = fmaf(-2.0f, __builtin_amdgcn_rcpf(y + 1.0f), 1.0f);
                sum = fmaf(r, swv[nf], sum);
            }
            sum += __shfl_xor(sum, 1);
            sum += __shfl_xor(sum, 2);
            sum += __shfl_xor(sum, 4);
            sum += __shfl_xor(sum, 8);
            if (l15 == 0) partial[row_l][wn] = sum;
        }
    }
    __syncthreads();
    if (t < 256) {
        const int r = t >> 1, hh = t & 1;
        const float sc = partial[r][hh * 2] + partial[r][hh * 2 + 1] + sb;
        align_out[(size_t)(b * 8 + hp * 2 + hh) * 4096 + kk0 + r] = sc;
    }
}

// ---------- K4: softmax over k ----------
__global__ __launch_bounds__(256) void softmax_kernel(float* __restrict__ align_o) {
    const int bh = blockIdx.x;
    float* row = align_o + (size_t)bh * 4096;
    const int t = threadIdx.x;
    float v[16];
    float m = -1e30f;
#pragma unroll
    for (int i = 0; i < 16; ++i) {
        v[i] = row[i * 256 + t];
        m = fmaxf(m, v[i]);
    }
#pragma unroll
    for (int off = 32; off; off >>= 1) m = fmaxf(m, __shfl_xor(m, off));
    __shared__ float sm[4], ss[4];
    const int wid = t >> 6;
    if ((t & 63) == 0) sm[wid] = m;
    __syncthreads();
    m = fmaxf(fmaxf(sm[0], sm[1]), fmaxf(sm[2], sm[3]));
    float s = 0.f;
#pragma unroll
    for (int i = 0; i < 16; ++i) {
        v[i] = __expf(v[i] - m);
        s += v[i];
    }
#pragma unroll
    for (int off = 32; off; off >>= 1) s += __shfl_xor(s, off);
    if ((t & 63) == 0) ss[wid] = s;
    __syncthreads();
    s = ss[0] + ss[1] + ss[2] + ss[3];
    const float inv = 1.f / s;
#pragma unroll
    for (int i = 0; i < 16; ++i) row[i * 256 + t] = v[i] * inv;
}

// ---------- K5: split-K context partials ----------
__global__ __launch_bounds__(256) void ctx_partial_kernel(
        const float* __restrict__ value, const float* __restrict__ align_o,
        float* __restrict__ pctx) {
    const int s = blockIdx.x;    // 0..31
    const int bh = blockIdx.y;   // 0..127
    const int b = bh >> 3, h = bh & 7;
    const int t = threadIdx.x;
    const int d4 = (t & 31) * 4;
    const int kg = t >> 5;
    const float* arow = align_o + (size_t)bh * 4096 + s * 128;
    const float* vbase = value + ((size_t)(b * 4096 + s * 128)) * 1024 + h * 128 + d4;
    float4 acc = {0.f, 0.f, 0.f, 0.f};
    for (int i = 0; i < 16; ++i) {
        const int kk = i * 8 + kg;
        const float a = arow[kk];
        const float4 v = *reinterpret_cast<const float4*>(vbase + (size_t)kk * 1024);
        acc.x += a * v.x; acc.y += a * v.y; acc.z += a * v.z; acc.w += a * v.w;
    }
    __shared__ float sm2[8][128];
    *reinterpret_cast<float4*>(&sm2[kg][d4]) = acc;
    __syncthreads();
    if (t < 128) {
        float s0 = 0.f;
#pragma unroll
        for (int gg = 0; gg < 8; ++gg) s0 += sm2[gg][t];
        pctx[((size_t)bh * 32 + s) * 128 + t] = s0;
    }
}

// ---------- K6: reduce context partials ----------
__global__ __launch_bounds__(128) void ctx_reduce_kernel(
        const float* __restrict__ pctx, float* __restrict__ out) {
    const int bh = blockIdx.x;
    const int t = threadIdx.x;
    float acc = 0.f;
    for (int s2 = 0; s2 < 32; ++s2) acc += pctx[((size_t)bh * 32 + s2) * 128 + t];
    out[(size_t)bh * 128 + t] = acc;
}

extern "C" void kernel_launch(void* const* d_in, const int* in_sizes, int n_in,
                              void* d_out, int out_size, void* d_ws, size_t ws_size,
                              hipStream_t stream) {
    const float* query   = (const float*)d_in[0];
    const float* key_in  = (const float*)d_in[1];
    const float* value   = (const float*)d_in[2];
    const float* pa      = (const float*)d_in[3];
    const float* conv_w  = (const float*)d_in[4];
    const float* conv_b  = (const float*)d_in[5];
    const float* w_u     = (const float*)d_in[6];
    const float* w_q     = (const float*)d_in[7];
    const float* w_v     = (const float*)d_in[8];
    const float* bias    = (const float*)d_in[9];
    const float* score_w = (const float*)d_in[10];
    const float* score_b = (const float*)d_in[11];

    float* out = (float*)d_out;
    float* ctx_out = out;                 // [128,128]
    float* align_out = out + 16384;       // [16,8,4096]

    char* ws = (char*)d_ws;
    const size_t OFF_Q    = 0;                        // 64 KB
    const size_t OFF_WVT  = 65536;                    // 2 MB (tiled bf16)
    const size_t OFF_PCTX = OFF_WVT + 2097152;        // 2 MB
    const size_t OFF_LE   = OFF_PCTX + 2097152;       // 33.55 MB

    float* ws_q            = (float*)(ws + OFF_Q);
    unsigned short* ws_wvT = (unsigned short*)(ws + OFF_WVT);
    float* ws_pctx         = (float*)(ws + OFF_PCTX);
    float* ws_le           = (float*)(ws + OFF_LE);

    hipLaunchKernelGGL(wv_tile_kernel, dim3(8, 32), dim3(256), 0, stream, w_v, ws_wvT);
    hipLaunchKernelGGL(qproj_kernel, dim3(16), dim3(1024), 0, stream, query, w_q, ws_q);
    hipLaunchKernelGGL(loc_le_kernel, dim3(16, 32), dim3(256), 0, stream,
                       pa, conv_w, conv_b, w_u, ws_le);
    hipLaunchKernelGGL(gemm_score_kernel, dim3(2048), dim3(512), 0, stream,
                       key_in, ws_wvT, ws_le, ws_q, bias, score_w, score_b, align_out);
    hipLaunchKernelGGL(softmax_kernel, dim3(128), dim3(256), 0, stream, align_out);
    hipLaunchKernelGGL(ctx_partial_kernel, dim3(32, 128), dim3(256), 0, stream, value, align_out, ws_pctx);
    hipLaunchKernelGGL(ctx_reduce_kernel, dim3(128), dim3(128), 0, stream, ws_pctx, ctx_out);
}

// Round 16
// 302.776 us; speedup vs baseline: 1.4278x; 1.1395x over previous
//
#include <hip/hip_runtime.h>
#include <hip/hip_bf16.h>
#include <cstdint>

typedef __attribute__((ext_vector_type(8))) short bf16x8;
typedef __attribute__((ext_vector_type(4))) float f32x4;
typedef __attribute__((ext_vector_type(8))) unsigned short u16x8;
typedef __attribute__((ext_vector_type(4))) unsigned int u32x4;

__device__ __forceinline__ unsigned short f2bf(float f) {
    unsigned int u = __float_as_uint(f);
    unsigned int r = (u + 0x7fffu + ((u >> 16) & 1u)) >> 16;
    return (unsigned short)r;
}

__device__ __forceinline__ float tanh_fast(float x) {
    return 1.0f - 2.0f / (__expf(2.0f * x) + 1.0f);
}

#define GLDS(SRC, DST) __builtin_amdgcn_global_load_lds(                         \
        (const __attribute__((address_space(1))) void*)(SRC),                    \
        (__attribute__((address_space(3))) void*)(DST), 16, 0, 0)

// ---------- K0: w_v -> bf16 fragment-tiled B (per head, BK=32 layout) ----------
__global__ __launch_bounds__(256) void wv_tile_kernel(
        const float* __restrict__ wv, unsigned short* __restrict__ out) {
    __shared__ float tile[32][129];
    const int h = blockIdx.x;    // 0..7
    const int kt = blockIdx.y;   // 0..31
    const int t = threadIdx.x;
    for (int i = t; i < 1024; i += 256) {
        const int fl = i >> 5;
        const int e4 = (i & 31) * 4;
        const float4 v = *reinterpret_cast<const float4*>(
            wv + (size_t)(kt * 32 + fl) * 1024 + h * 128 + e4);
        tile[fl][e4 + 0] = v.x; tile[fl][e4 + 1] = v.y;
        tile[fl][e4 + 2] = v.z; tile[fl][e4 + 3] = v.w;
    }
    __syncthreads();
#pragma unroll
    for (int cc2 = 0; cc2 < 2; ++cc2) {
        const int c = cc2 * 256 + t;
        const int cb = c >> 6, kg = (c >> 4) & 3, ccl = c & 15;
        const int e_local = cb * 16 + ccl;
        u16x8 u;
#pragma unroll
        for (int jj = 0; jj < 8; ++jj) u[jj] = f2bf(tile[kg * 8 + jj][e_local]);
        *reinterpret_cast<u16x8*>(out + (((size_t)h * 32 + kt) * 512 + c) * 8) = u;
    }
}

// ---------- K1: q projection (128 blocks: one (b,h) pair each) ----------
__global__ __launch_bounds__(128) void qproj_kernel(
        const float* __restrict__ query, const float* __restrict__ w_q,
        float* __restrict__ ws_q) {
    __shared__ float qs[1024];
    const int bh = blockIdx.x;
    const int b = bh >> 3, h = bh & 7;
    const int t = threadIdx.x;
    for (int i = t; i < 1024; i += 128) qs[i] = query[(size_t)b * 1024 + i];
    __syncthreads();
    float acc = 0.f;
    const float* wcol = w_q + h * 128 + t;
    for (int f = 0; f < 1024; ++f) acc = fmaf(qs[f], wcol[(size_t)f * 1024], acc);
    ws_q[(size_t)bh * 128 + t] = acc;
}

// ---------- K2: fused conv1d + location-energy ----------
__global__ __launch_bounds__(256) void loc_le_kernel(
        const float* __restrict__ pa, const float* __restrict__ conv_w,
        const float* __restrict__ conv_b, const float* __restrict__ w_u,
        float* __restrict__ le) {
    __shared__ float pas[8][132];
    __shared__ float wu_s[10][128];
    __shared__ float cw[240];
    __shared__ float cb[16];
    const int b = blockIdx.x, k0 = blockIdx.y * 128;
    const int t = threadIdx.x;
    for (int i = t; i < 8 * 130; i += 256) {
        const int hh = i / 130, kk = i % 130;
        const int gk = k0 + kk - 1;
        pas[hh][kk] = (gk >= 0 && gk < 4096) ? pa[((size_t)(b * 8 + hh)) * 4096 + gk] : 0.f;
    }
    for (int i = t; i < 1280; i += 256) wu_s[i >> 7][i & 127] = w_u[i];
    if (t < 240) cw[t] = conv_w[t];
    if (t < 10) cb[t] = conv_b[t];
    __syncthreads();
    const int k = t >> 1;
    const int d0 = (t & 1) * 64;
    float lc[10];
#pragma unroll
    for (int c = 0; c < 10; ++c) {
        float acc = cb[c];
#pragma unroll
        for (int hh = 0; hh < 8; ++hh) {
            acc += pas[hh][k] * cw[(c * 8 + hh) * 3 + 0]
                 + pas[hh][k + 1] * cw[(c * 8 + hh) * 3 + 1]
                 + pas[hh][k + 2] * cw[(c * 8 + hh) * 3 + 2];
        }
        lc[c] = acc;
    }
    float* dst = le + ((size_t)(b * 4096) + k0 + k) * 128 + d0;
#pragma unroll
    for (int dd = 0; dd < 64; dd += 4) {
        float4 o;
#pragma unroll
        for (int jj = 0; jj < 4; ++jj) {
            float s = 0.f;
#pragma unroll
            for (int c = 0; c < 10; ++c) s += lc[c] * wu_s[c][d0 + dd + jj];
            ((float*)&o)[jj] = tanh_fast(s);
        }
        *reinterpret_cast<float4*>(dst + dd) = o;
    }
}

// ---------- K3: GEMM, ring-3 LDS, ONE barrier per kt ----------
// BM=128, BN=256 (2 heads), BK=32; 512 thr, 8 waves (2M x 4N), wave 64x64.
// A: fp32 coalesced -> regs -> cvt_pk -> XOR-swizzled ds_write.
// B: pre-tiled bf16 via GLDS, 1 kt ahead. Ring-3 buffers make re-write distance
// 3 kts -> the end-of-kt barrier is unnecessary; B(cur) certified by WRITEA's
// compiler-inserted vmcnt (A-regs newer than B(cur) in VMEM queue).
#define NT 32
__global__ __launch_bounds__(512) void gemm_score_kernel(
        const float* __restrict__ key_in, const unsigned short* __restrict__ wvT_tiled,
        const float* __restrict__ le,
        const float* __restrict__ ws_q, const float* __restrict__ bias,
        const float* __restrict__ score_w, const float* __restrict__ score_b,
        float* __restrict__ align_out) {
    __shared__ __align__(16) unsigned short As[3][4096];    // 24 KB
    __shared__ __align__(16) unsigned short Bs[3][8192];    // 48 KB
    __shared__ float qb_sm[256], sw_sm[128];
    __shared__ float partial[128][4];

    const int t = threadIdx.x;
    const int lane = t & 63, wid = t >> 6;
    const int wm = wid >> 2;          // 0..1 : M-half
    const int wn = wid & 3;           // 0..3 : (head, d-half)

    // XCD swizzle: the 4 head-pair blocks of one panel adjacent on one XCD
    const int fid = blockIdx.x;       // 0..2047
    const int x = fid & 7, j = fid >> 3;     // j: 0..255
    const int bm = x * 64 + (j >> 2);        // panel 0..511 (128 rows)
    const int hp = j & 3;                    // head-pair 0..3
    const int b = bm >> 5;
    const int kk0 = (bm & 31) << 7;

    if (t < 256) {
        const int hh = t >> 7, d = t & 127;
        qb_sm[t] = ws_q[(size_t)(b * 8 + hp * 2 + hh) * 128 + d] + bias[d];
        if (t < 128) sw_sm[t] = score_w[t];
    }

    // ---- A staging: thread t reads row r_=t>>2, kseg ks=t&3 (coalesced 128B/4 lanes)
    const int r_ = t >> 2, ks = t & 3;
    const float* aRow = key_in + ((size_t)(b * 4096 + kk0) + r_) * 1024 + ks * 8;
    const int cW = (t >> 6) * 64 + ks * 16 + (r_ & 15);
    const int dst0 = (cW ^ (ks | ((ks & 1) << 2))) * 8;            // ushort idx

    // fragment-read lane swizzle (same involution): kg = lane>>4
    const int kgR = lane >> 4;
    const int laneSwz = lane ^ (kgR | ((kgR & 1) << 2));

    // ---- B staging: thread stages two 16B chunks of one head ----
    const unsigned short* bT = wvT_tiled
        + (size_t)(hp * 2 + (t >> 8)) * 131072 + (t & 255) * 8;
    const int dstB = (t >> 8) * 4096 + (t & 255) * 8;              // ushort idx

    float4 st0, st1;

#define LOADA(KT) {                                                               \
        const float* p_ = aRow + (KT) * 32;                                       \
        st0 = *reinterpret_cast<const float4*>(p_);                               \
        st1 = *reinterpret_cast<const float4*>(p_ + 4); }

#define WRITEA(BUF) {                                                             \
        __hip_bfloat162 h0_ = __float22bfloat162_rn({st0.x, st0.y});              \
        __hip_bfloat162 h1_ = __float22bfloat162_rn({st0.z, st0.w});              \
        __hip_bfloat162 h2_ = __float22bfloat162_rn({st1.x, st1.y});              \
        __hip_bfloat162 h3_ = __float22bfloat162_rn({st1.z, st1.w});              \
        u32x4 u_;                                                                 \
        u_[0] = *reinterpret_cast<unsigned int*>(&h0_);                           \
        u_[1] = *reinterpret_cast<unsigned int*>(&h1_);                           \
        u_[2] = *reinterpret_cast<unsigned int*>(&h2_);                           \
        u_[3] = *reinterpret_cast<unsigned int*>(&h3_);                           \
        *reinterpret_cast<u32x4*>(&As[BUF][dst0]) = u_; }

#define STAGE_B(BUF, KT) {                                                        \
        GLDS(bT + (size_t)(KT) * 4096, &Bs[BUF][dstB]);                           \
        GLDS(bT + (size_t)(KT) * 4096 + 2048, &Bs[BUF][dstB + 2048]); }

    f32x4 acc[4][4] = {};

    // prologue: B(0)->buf0, A(0)->buf0 (regs->LDS, waits A0+B0), preload A(1)
    LOADA(0);
    STAGE_B(0, 0);
    WRITEA(0);
    LOADA(1);

    for (int kt = 0; kt < NT; ++kt) {
        const int cur = kt % 3;
        const int nxt = (kt + 1) % 3;
        STAGE_B(nxt, (kt + 1) & (NT - 1));   // wraps harmlessly on last iter
        WRITEA(nxt);        // regs A(kt+1); implicit vmcnt also certifies B(kt)
        LOADA((kt + 2) & (NT - 1));
        asm volatile("s_waitcnt lgkmcnt(0)\n\t"
                     "s_barrier" ::: "memory");

        bf16x8 af[4], bg[4];
#pragma unroll
        for (int mf = 0; mf < 4; ++mf)
            af[mf] = *reinterpret_cast<const bf16x8*>(
                &As[cur][((wm * 4 + mf) * 64 + laneSwz) * 8]);
#pragma unroll
        for (int nf = 0; nf < 4; ++nf)
            bg[nf] = *reinterpret_cast<const bf16x8*>(
                &Bs[cur][(wn >> 1) * 4096 + ((wn & 1) * 4 + nf) * 512 + lane * 8]);
        __builtin_amdgcn_s_setprio(1);
#pragma unroll
        for (int mf = 0; mf < 4; ++mf)
#pragma unroll
            for (int nf = 0; nf < 4; ++nf)
                acc[mf][nf] = __builtin_amdgcn_mfma_f32_16x16x32_bf16(
                    af[mf], bg[nf], acc[mf][nf], 0, 0, 0);
        __builtin_amdgcn_s_setprio(0);
        // no end-of-kt barrier: ring-3 re-write distance covers the hazard
    }

    // ---- epilogue: score = sum_d tanh(kproj + q + bias + le) * sw ----
    const float K2 = 2.8853900817779268f;
    const float sb = score_b[0];
    const int g = lane >> 4;
    const int l15 = lane & 15;
    float kqb[4], swv[4];
#pragma unroll
    for (int nf = 0; nf < 4; ++nf) {
        const int d128 = (wn & 1) * 64 + nf * 16 + l15;
        kqb[nf] = qb_sm[(wn >> 1) * 128 + d128] * K2;
        swv[nf] = sw_sm[d128];
    }
    const float* leB = le + ((size_t)(b * 4096 + kk0) + wm * 64 + g * 4) * 128
                       + (wn & 1) * 64 + l15;

#pragma unroll
    for (int mf = 0; mf < 4; ++mf) {
        float lv[16];
#pragma unroll
        for (int jj = 0; jj < 4; ++jj)
#pragma unroll
            for (int nf = 0; nf < 4; ++nf)
                lv[jj * 4 + nf] = leB[(size_t)(mf * 16 + jj) * 128 + nf * 16];
#pragma unroll
        for (int jj = 0; jj < 4; ++jj) {
            const int row_l = wm * 64 + mf * 16 + g * 4 + jj;
            float sum = 0.f;
#pragma unroll
            for (int nf = 0; nf < 4; ++nf) {
                const float m = fmaf(K2, lv[jj * 4 + nf], kqb[nf]);
                const float tt = fmaf(K2, acc[mf][nf][jj], m);
                const float y = __builtin_amdgcn_exp2f(tt);
                const float r = fmaf(-2.0f, __builtin_amdgcn_rcpf(y + 1.0f), 1.0f);
                sum = fmaf(r, swv[nf], sum);
            }
            sum += __shfl_xor(sum, 1);
            sum += __shfl_xor(sum, 2);
            sum += __shfl_xor(sum, 4);
            sum += __shfl_xor(sum, 8);
            if (l15 == 0) partial[row_l][wn] = sum;
        }
    }
    __syncthreads();
    if (t < 256) {
        const int r = t >> 1, hh = t & 1;
        const float sc = partial[r][hh * 2] + partial[r][hh * 2 + 1] + sb;
        align_out[(size_t)(b * 8 + hp * 2 + hh) * 4096 + kk0 + r] = sc;
    }
}

// ---------- K4: softmax over k ----------
__global__ __launch_bounds__(256) void softmax_kernel(float* __restrict__ align_o) {
    const int bh = blockIdx.x;
    float* row = align_o + (size_t)bh * 4096;
    const int t = threadIdx.x;
    float v[16];
    float m = -1e30f;
#pragma unroll
    for (int i = 0; i < 16; ++i) {
        v[i] = row[i * 256 + t];
        m = fmaxf(m, v[i]);
    }
#pragma unroll
    for (int off = 32; off; off >>= 1) m = fmaxf(m, __shfl_xor(m, off));
    __shared__ float sm[4], ss[4];
    const int wid = t >> 6;
    if ((t & 63) == 0) sm[wid] = m;
    __syncthreads();
    m = fmaxf(fmaxf(sm[0], sm[1]), fmaxf(sm[2], sm[3]));
    float s = 0.f;
#pragma unroll
    for (int i = 0; i < 16; ++i) {
        v[i] = __expf(v[i] - m);
        s += v[i];
    }
#pragma unroll
    for (int off = 32; off; off >>= 1) s += __shfl_xor(s, off);
    if ((t & 63) == 0) ss[wid] = s;
    __syncthreads();
    s = ss[0] + ss[1] + ss[2] + ss[3];
    const float inv = 1.f / s;
#pragma unroll
    for (int i = 0; i < 16; ++i) row[i * 256 + t] = v[i] * inv;
}

// ---------- K5: split-K context partials ----------
__global__ __launch_bounds__(256) void ctx_partial_kernel(
        const float* __restrict__ value, const float* __restrict__ align_o,
        float* __restrict__ pctx) {
    const int s = blockIdx.x;    // 0..31
    const int bh = blockIdx.y;   // 0..127
    const int b = bh >> 3, h = bh & 7;
    const int t = threadIdx.x;
    const int d4 = (t & 31) * 4;
    const int kg = t >> 5;
    const float* arow = align_o + (size_t)bh * 4096 + s * 128;
    const float* vbase = value + ((size_t)(b * 4096 + s * 128)) * 1024 + h * 128 + d4;
    float4 acc = {0.f, 0.f, 0.f, 0.f};
    for (int i = 0; i < 16; ++i) {
        const int kk = i * 8 + kg;
        const float a = arow[kk];
        const float4 v = *reinterpret_cast<const float4*>(vbase + (size_t)kk * 1024);
        acc.x += a * v.x; acc.y += a * v.y; acc.z += a * v.z; acc.w += a * v.w;
    }
    __shared__ float sm2[8][128];
    *reinterpret_cast<float4*>(&sm2[kg][d4]) = acc;
    __syncthreads();
    if (t < 128) {
        float s0 = 0.f;
#pragma unroll
        for (int gg = 0; gg < 8; ++gg) s0 += sm2[gg][t];
        pctx[((size_t)bh * 32 + s) * 128 + t] = s0;
    }
}

// ---------- K6: reduce context partials ----------
__global__ __launch_bounds__(128) void ctx_reduce_kernel(
        const float* __restrict__ pctx, float* __restrict__ out) {
    const int bh = blockIdx.x;
    const int t = threadIdx.x;
    float acc = 0.f;
    for (int s2 = 0; s2 < 32; ++s2) acc += pctx[((size_t)bh * 32 + s2) * 128 + t];
    out[(size_t)bh * 128 + t] = acc;
}

extern "C" void kernel_launch(void* const* d_in, const int* in_sizes, int n_in,
                              void* d_out, int out_size, void* d_ws, size_t ws_size,
                              hipStream_t stream) {
    const float* query   = (const float*)d_in[0];
    const float* key_in  = (const float*)d_in[1];
    const float* value   = (const float*)d_in[2];
    const float* pa      = (const float*)d_in[3];
    const float* conv_w  = (const float*)d_in[4];
    const float* conv_b  = (const float*)d_in[5];
    const float* w_u     = (const float*)d_in[6];
    const float* w_q     = (const float*)d_in[7];
    const float* w_v     = (const float*)d_in[8];
    const float* bias    = (const float*)d_in[9];
    const float* score_w = (const float*)d_in[10];
    const float* score_b = (const float*)d_in[11];

    float* out = (float*)d_out;
    float* ctx_out = out;                 // [128,128]
    float* align_out = out + 16384;       // [16,8,4096]

    char* ws = (char*)d_ws;
    const size_t OFF_Q    = 0;                        // 64 KB
    const size_t OFF_WVT  = 65536;                    // 2 MB (tiled bf16)
    const size_t OFF_PCTX = OFF_WVT + 2097152;        // 2 MB
    const size_t OFF_LE   = OFF_PCTX + 2097152;       // 33.55 MB

    float* ws_q            = (float*)(ws + OFF_Q);
    unsigned short* ws_wvT = (unsigned short*)(ws + OFF_WVT);
    float* ws_pctx         = (float*)(ws + OFF_PCTX);
    float* ws_le           = (float*)(ws + OFF_LE);

    hipLaunchKernelGGL(wv_tile_kernel, dim3(8, 32), dim3(256), 0, stream, w_v, ws_wvT);
    hipLaunchKernelGGL(qproj_kernel, dim3(128), dim3(128), 0, stream, query, w_q, ws_q);
    hipLaunchKernelGGL(loc_le_kernel, dim3(16, 32), dim3(256), 0, stream,
                       pa, conv_w, conv_b, w_u, ws_le);
    hipLaunchKernelGGL(gemm_score_kernel, dim3(2048), dim3(512), 0, stream,
                       key_in, ws_wvT, ws_le, ws_q, bias, score_w, score_b, align_out);
    hipLaunchKernelGGL(softmax_kernel, dim3(128), dim3(256), 0, stream, align_out);
    hipLaunchKernelGGL(ctx_partial_kernel, dim3(32, 128), dim3(256), 0, stream, value, align_out, ws_pctx);
    hipLaunchKernelGGL(ctx_reduce_kernel, dim3(128), dim3(128), 0, stream, ws_pctx, ctx_out);
}

// Round 17
// 297.772 us; speedup vs baseline: 1.4518x; 1.0168x over previous
//
#include <hip/hip_runtime.h>
#include <hip/hip_bf16.h>
#include <cstdint>

typedef __attribute__((ext_vector_type(8))) short bf16x8;
typedef __attribute__((ext_vector_type(4))) float f32x4;
typedef __attribute__((ext_vector_type(8))) unsigned short u16x8;
typedef __attribute__((ext_vector_type(4))) unsigned int u32x4;

__device__ __forceinline__ unsigned short f2bf(float f) {
    unsigned int u = __float_as_uint(f);
    unsigned int r = (u + 0x7fffu + ((u >> 16) & 1u)) >> 16;
    return (unsigned short)r;
}

__device__ __forceinline__ float tanh_fast(float x) {
    return 1.0f - 2.0f / (__expf(2.0f * x) + 1.0f);
}

#define GLDS(SRC, DST) __builtin_amdgcn_global_load_lds(                         \
        (const __attribute__((address_space(1))) void*)(SRC),                    \
        (__attribute__((address_space(3))) void*)(DST), 16, 0, 0)

// ---------- K0: fused prep: wv_tile (blocks 0..255) | qproj (256..383) |
//                            loc_le (384..895) ----------
__global__ __launch_bounds__(256) void prep_kernel(
        const float* __restrict__ wv, unsigned short* __restrict__ wvT,
        const float* __restrict__ query, const float* __restrict__ w_q,
        float* __restrict__ ws_q,
        const float* __restrict__ pa, const float* __restrict__ conv_w,
        const float* __restrict__ conv_b, const float* __restrict__ w_u,
        float* __restrict__ le) {
    __shared__ __align__(16) char smem[16640];
    const int bid = blockIdx.x;
    const int t = threadIdx.x;

    if (bid < 256) {
        // ---- wv -> bf16 fragment-tiled B (per head, BK=32 layout) ----
        float (*tile)[129] = reinterpret_cast<float(*)[129]>(smem);
        const int h = bid >> 5, kt = bid & 31;
        for (int i = t; i < 1024; i += 256) {
            const int fl = i >> 5;
            const int e4 = (i & 31) * 4;
            const float4 v = *reinterpret_cast<const float4*>(
                wv + (size_t)(kt * 32 + fl) * 1024 + h * 128 + e4);
            tile[fl][e4 + 0] = v.x; tile[fl][e4 + 1] = v.y;
            tile[fl][e4 + 2] = v.z; tile[fl][e4 + 3] = v.w;
        }
        __syncthreads();
#pragma unroll
        for (int cc2 = 0; cc2 < 2; ++cc2) {
            const int c = cc2 * 256 + t;
            const int cb = c >> 6, kg = (c >> 4) & 3, ccl = c & 15;
            const int e_local = cb * 16 + ccl;
            u16x8 u;
#pragma unroll
            for (int jj = 0; jj < 8; ++jj) u[jj] = f2bf(tile[kg * 8 + jj][e_local]);
            *reinterpret_cast<u16x8*>(wvT + (((size_t)h * 32 + kt) * 512 + c) * 8) = u;
        }
    } else if (bid < 384) {
        // ---- q projection: one (b,h) per block, 128 active compute lanes ----
        float* qs = reinterpret_cast<float*>(smem);
        const int bh = bid - 256;
        const int b = bh >> 3, h = bh & 7;
        for (int i = t; i < 1024; i += 256) qs[i] = query[(size_t)b * 1024 + i];
        __syncthreads();
        if (t < 128) {
            float acc = 0.f;
            const float* wcol = w_q + h * 128 + t;
            for (int f = 0; f < 1024; ++f) acc = fmaf(qs[f], wcol[(size_t)f * 1024], acc);
            ws_q[(size_t)bh * 128 + t] = acc;
        }
    } else {
        // ---- fused conv1d + location-energy ----
        float* pas = reinterpret_cast<float*>(smem);            // 8*132
        float* wu_s = pas + 1056;                               // 10*128
        float* cw = wu_s + 1280;                                // 240
        float* cb = cw + 240;                                   // 16
        const int idx = bid - 384;
        const int b = idx >> 5, k0 = (idx & 31) * 128;
        for (int i = t; i < 8 * 130; i += 256) {
            const int hh = i / 130, kk = i % 130;
            const int gk = k0 + kk - 1;
            pas[hh * 132 + kk] = (gk >= 0 && gk < 4096)
                ? pa[((size_t)(b * 8 + hh)) * 4096 + gk] : 0.f;
        }
        for (int i = t; i < 1280; i += 256) wu_s[i] = w_u[i];
        if (t < 240) cw[t] = conv_w[t];
        if (t < 10) cb[t] = conv_b[t];
        __syncthreads();
        const int k = t >> 1;
        const int d0 = (t & 1) * 64;
        float lc[10];
#pragma unroll
        for (int c = 0; c < 10; ++c) {
            float acc = cb[c];
#pragma unroll
            for (int hh = 0; hh < 8; ++hh) {
                acc += pas[hh * 132 + k] * cw[(c * 8 + hh) * 3 + 0]
                     + pas[hh * 132 + k + 1] * cw[(c * 8 + hh) * 3 + 1]
                     + pas[hh * 132 + k + 2] * cw[(c * 8 + hh) * 3 + 2];
            }
            lc[c] = acc;
        }
        float* dst = le + ((size_t)(b * 4096) + k0 + k) * 128 + d0;
#pragma unroll
        for (int dd = 0; dd < 64; dd += 4) {
            float4 o;
#pragma unroll
            for (int jj = 0; jj < 4; ++jj) {
                float s = 0.f;
#pragma unroll
                for (int c = 0; c < 10; ++c) s += lc[c] * wu_s[c * 128 + d0 + dd + jj];
                ((float*)&o)[jj] = tanh_fast(s);
            }
            *reinterpret_cast<float4*>(dst + dd) = o;
        }
    }
}

// ---------- K3: GEMM, ring-3 LDS, one barrier/kt, post-barrier B staging ----
// BM=128, BN=256 (2 heads), BK=32; 512 thr, 8 waves (2M x 4N), wave 64x64.
// A: fp32 coalesced -> regs -> cvt_pk -> XOR-swizzled ds_write.
// B: pre-tiled bf16 via GLDS, staged 2 kts ahead AFTER the barrier (buffer
// (kt+2)%3 is provably idle there). B(kt) certified by WRITEA's implicit
// vmcnt (A(kt+1)-regs older than only B(kt+1)/B(kt+2) in VMEM queue).
#define NT 32
__global__ __launch_bounds__(512) void gemm_score_kernel(
        const float* __restrict__ key_in, const unsigned short* __restrict__ wvT_tiled,
        const float* __restrict__ le,
        const float* __restrict__ ws_q, const float* __restrict__ bias,
        const float* __restrict__ score_w, const float* __restrict__ score_b,
        float* __restrict__ align_out) {
    __shared__ __align__(16) unsigned short As[3][4096];    // 24 KB
    __shared__ __align__(16) unsigned short Bs[3][8192];    // 48 KB
    __shared__ float qb_sm[256], sw_sm[128];
    __shared__ float partial[128][4];

    const int t = threadIdx.x;
    const int lane = t & 63, wid = t >> 6;
    const int wm = wid >> 2;          // 0..1 : M-half
    const int wn = wid & 3;           // 0..3 : (head, d-half)

    // XCD swizzle: the 4 head-pair blocks of one panel adjacent on one XCD
    const int fid = blockIdx.x;       // 0..2047
    const int x = fid & 7, j = fid >> 3;     // j: 0..255
    const int bm = x * 64 + (j >> 2);        // panel 0..511 (128 rows)
    const int hp = j & 3;                    // head-pair 0..3
    const int b = bm >> 5;
    const int kk0 = (bm & 31) << 7;

    if (t < 256) {
        const int hh = t >> 7, d = t & 127;
        qb_sm[t] = ws_q[(size_t)(b * 8 + hp * 2 + hh) * 128 + d] + bias[d];
        if (t < 128) sw_sm[t] = score_w[t];
    }

    // ---- A staging: thread t reads row r_=t>>2, kseg ks=t&3 (coalesced 128B/4 lanes)
    const int r_ = t >> 2, ks = t & 3;
    const float* aRow = key_in + ((size_t)(b * 4096 + kk0) + r_) * 1024 + ks * 8;
    const int cW = (t >> 6) * 64 + ks * 16 + (r_ & 15);
    const int dst0 = (cW ^ (ks | ((ks & 1) << 2))) * 8;            // ushort idx

    // fragment-read lane swizzle (same involution): kg = lane>>4
    const int kgR = lane >> 4;
    const int laneSwz = lane ^ (kgR | ((kgR & 1) << 2));

    // ---- B staging: thread stages two 16B chunks of one head ----
    const unsigned short* bT = wvT_tiled
        + (size_t)(hp * 2 + (t >> 8)) * 131072 + (t & 255) * 8;
    const int dstB = (t >> 8) * 4096 + (t & 255) * 8;              // ushort idx

    float4 st0, st1;

#define LOADA(KT) {                                                               \
        const float* p_ = aRow + (KT) * 32;                                       \
        st0 = *reinterpret_cast<const float4*>(p_);                               \
        st1 = *reinterpret_cast<const float4*>(p_ + 4); }

#define WRITEA(BUF) {                                                             \
        __hip_bfloat162 h0_ = __float22bfloat162_rn({st0.x, st0.y});              \
        __hip_bfloat162 h1_ = __float22bfloat162_rn({st0.z, st0.w});              \
        __hip_bfloat162 h2_ = __float22bfloat162_rn({st1.x, st1.y});              \
        __hip_bfloat162 h3_ = __float22bfloat162_rn({st1.z, st1.w});              \
        u32x4 u_;                                                                 \
        u_[0] = *reinterpret_cast<unsigned int*>(&h0_);                           \
        u_[1] = *reinterpret_cast<unsigned int*>(&h1_);                           \
        u_[2] = *reinterpret_cast<unsigned int*>(&h2_);                           \
        u_[3] = *reinterpret_cast<unsigned int*>(&h3_);                           \
        *reinterpret_cast<u32x4*>(&As[BUF][dst0]) = u_; }

#define STAGE_B(BUF, KT) {                                                        \
        GLDS(bT + (size_t)(KT) * 4096, &Bs[BUF][dstB]);                           \
        GLDS(bT + (size_t)(KT) * 4096 + 2048, &Bs[BUF][dstB + 2048]); }

    f32x4 acc[4][4] = {};

    // prologue: B(0)->buf0, B(1)->buf1, A(0)->buf0 (regs->LDS), preload A(1)
    LOADA(0);
    STAGE_B(0, 0);
    STAGE_B(1, 1);
    WRITEA(0);
    LOADA(1);

    for (int kt = 0; kt < NT; ++kt) {
        const int cur = kt % 3;
        const int nxt = (kt + 1) % 3;
        const int pre = (kt + 2) % 3;
        WRITEA(nxt);        // regs A(kt+1); implicit vmcnt also certifies B(kt)
        LOADA((kt + 2) & (NT - 1));
        asm volatile("s_waitcnt lgkmcnt(0)\n\t"
                     "s_barrier" ::: "memory");
        STAGE_B(pre, (kt + 2) & (NT - 1));   // buffer pre idle after barrier

        bf16x8 af[4], bg[4];
#pragma unroll
        for (int mf = 0; mf < 4; ++mf)
            af[mf] = *reinterpret_cast<const bf16x8*>(
                &As[cur][((wm * 4 + mf) * 64 + laneSwz) * 8]);
#pragma unroll
        for (int nf = 0; nf < 4; ++nf)
            bg[nf] = *reinterpret_cast<const bf16x8*>(
                &Bs[cur][(wn >> 1) * 4096 + ((wn & 1) * 4 + nf) * 512 + lane * 8]);
        __builtin_amdgcn_s_setprio(1);
#pragma unroll
        for (int mf = 0; mf < 4; ++mf)
#pragma unroll
            for (int nf = 0; nf < 4; ++nf)
                acc[mf][nf] = __builtin_amdgcn_mfma_f32_16x16x32_bf16(
                    af[mf], bg[nf], acc[mf][nf], 0, 0, 0);
        __builtin_amdgcn_s_setprio(0);
        // no end-of-kt barrier: ring-3 re-write distance covers the hazard
    }

    // ---- epilogue: score = sum_d tanh(kproj + q + bias + le) * sw ----
    const float K2 = 2.8853900817779268f;
    const float sb = score_b[0];
    const int g = lane >> 4;
    const int l15 = lane & 15;
    float kqb[4], swv[4];
#pragma unroll
    for (int nf = 0; nf < 4; ++nf) {
        const int d128 = (wn & 1) * 64 + nf * 16 + l15;
        kqb[nf] = qb_sm[(wn >> 1) * 128 + d128] * K2;
        swv[nf] = sw_sm[d128];
    }
    const float* leB = le + ((size_t)(b * 4096 + kk0) + wm * 64 + g * 4) * 128
                       + (wn & 1) * 64 + l15;

#pragma unroll
    for (int mf = 0; mf < 4; ++mf) {
        float lv[16];
#pragma unroll
        for (int jj = 0; jj < 4; ++jj)
#pragma unroll
            for (int nf = 0; nf < 4; ++nf)
                lv[jj * 4 + nf] = leB[(size_t)(mf * 16 + jj) * 128 + nf * 16];
#pragma unroll
        for (int jj = 0; jj < 4; ++jj) {
            const int row_l = wm * 64 + mf * 16 + g * 4 + jj;
            float sum = 0.f;
#pragma unroll
            for (int nf = 0; nf < 4; ++nf) {
                const float m = fmaf(K2, lv[jj * 4 + nf], kqb[nf]);
                const float tt = fmaf(K2, acc[mf][nf][jj], m);
                const float y = __builtin_amdgcn_exp2f(tt);
                const float r = fmaf(-2.0f, __builtin_amdgcn_rcpf(y + 1.0f), 1.0f);
                sum = fmaf(r, swv[nf], sum);
            }
            sum += __shfl_xor(sum, 1);
            sum += __shfl_xor(sum, 2);
            sum += __shfl_xor(sum, 4);
            sum += __shfl_xor(sum, 8);
            if (l15 == 0) partial[row_l][wn] = sum;
        }
    }
    __syncthreads();
    if (t < 256) {
        const int r = t >> 1, hh = t & 1;
        const float sc = partial[r][hh * 2] + partial[r][hh * 2 + 1] + sb;
        align_out[(size_t)(b * 8 + hp * 2 + hh) * 4096 + kk0 + r] = sc;
    }
}

// ---------- K4: softmax over k ----------
__global__ __launch_bounds__(256) void softmax_kernel(float* __restrict__ align_o) {
    const int bh = blockIdx.x;
    float* row = align_o + (size_t)bh * 4096;
    const int t = threadIdx.x;
    float v[16];
    float m = -1e30f;
#pragma unroll
    for (int i = 0; i < 16; ++i) {
        v[i] = row[i * 256 + t];
        m = fmaxf(m, v[i]);
    }
#pragma unroll
    for (int off = 32; off; off >>= 1) m = fmaxf(m, __shfl_xor(m, off));
    __shared__ float sm[4], ss[4];
    const int wid = t >> 6;
    if ((t & 63) == 0) sm[wid] = m;
    __syncthreads();
    m = fmaxf(fmaxf(sm[0], sm[1]), fmaxf(sm[2], sm[3]));
    float s = 0.f;
#pragma unroll
    for (int i = 0; i < 16; ++i) {
        v[i] = __expf(v[i] - m);
        s += v[i];
    }
#pragma unroll
    for (int off = 32; off; off >>= 1) s += __shfl_xor(s, off);
    if ((t & 63) == 0) ss[wid] = s;
    __syncthreads();
    s = ss[0] + ss[1] + ss[2] + ss[3];
    const float inv = 1.f / s;
#pragma unroll
    for (int i = 0; i < 16; ++i) row[i * 256 + t] = v[i] * inv;
}

// ---------- K5: split-K context partials ----------
__global__ __launch_bounds__(256) void ctx_partial_kernel(
        const float* __restrict__ value, const float* __restrict__ align_o,
        float* __restrict__ pctx) {
    const int s = blockIdx.x;    // 0..31
    const int bh = blockIdx.y;   // 0..127
    const int b = bh >> 3, h = bh & 7;
    const int t = threadIdx.x;
    const int d4 = (t & 31) * 4;
    const int kg = t >> 5;
    const float* arow = align_o + (size_t)bh * 4096 + s * 128;
    const float* vbase = value + ((size_t)(b * 4096 + s * 128)) * 1024 + h * 128 + d4;
    float4 acc = {0.f, 0.f, 0.f, 0.f};
    for (int i = 0; i < 16; ++i) {
        const int kk = i * 8 + kg;
        const float a = arow[kk];
        const float4 v = *reinterpret_cast<const float4*>(vbase + (size_t)kk * 1024);
        acc.x += a * v.x; acc.y += a * v.y; acc.z += a * v.z; acc.w += a * v.w;
    }
    __shared__ float sm2[8][128];
    *reinterpret_cast<float4*>(&sm2[kg][d4]) = acc;
    __syncthreads();
    if (t < 128) {
        float s0 = 0.f;
#pragma unroll
        for (int gg = 0; gg < 8; ++gg) s0 += sm2[gg][t];
        pctx[((size_t)bh * 32 + s) * 128 + t] = s0;
    }
}

// ---------- K6: reduce context partials ----------
__global__ __launch_bounds__(128) void ctx_reduce_kernel(
        const float* __restrict__ pctx, float* __restrict__ out) {
    const int bh = blockIdx.x;
    const int t = threadIdx.x;
    float acc = 0.f;
    for (int s2 = 0; s2 < 32; ++s2) acc += pctx[((size_t)bh * 32 + s2) * 128 + t];
    out[(size_t)bh * 128 + t] = acc;
}

extern "C" void kernel_launch(void* const* d_in, const int* in_sizes, int n_in,
                              void* d_out, int out_size, void* d_ws, size_t ws_size,
                              hipStream_t stream) {
    const float* query   = (const float*)d_in[0];
    const float* key_in  = (const float*)d_in[1];
    const float* value   = (const float*)d_in[2];
    const float* pa      = (const float*)d_in[3];
    const float* conv_w  = (const float*)d_in[4];
    const float* conv_b  = (const float*)d_in[5];
    const float* w_u     = (const float*)d_in[6];
    const float* w_q     = (const float*)d_in[7];
    const float* w_v     = (const float*)d_in[8];
    const float* bias    = (const float*)d_in[9];
    const float* score_w = (const float*)d_in[10];
    const float* score_b = (const float*)d_in[11];

    float* out = (float*)d_out;
    float* ctx_out = out;                 // [128,128]
    float* align_out = out + 16384;       // [16,8,4096]

    char* ws = (char*)d_ws;
    const size_t OFF_Q    = 0;                        // 64 KB
    const size_t OFF_WVT  = 65536;                    // 2 MB (tiled bf16)
    const size_t OFF_PCTX = OFF_WVT + 2097152;        // 2 MB
    const size_t OFF_LE   = OFF_PCTX + 2097152;       // 33.55 MB

    float* ws_q            = (float*)(ws + OFF_Q);
    unsigned short* ws_wvT = (unsigned short*)(ws + OFF_WVT);
    float* ws_pctx         = (float*)(ws + OFF_PCTX);
    float* ws_le           = (float*)(ws + OFF_LE);

    hipLaunchKernelGGL(prep_kernel, dim3(896), dim3(256), 0, stream,
                       w_v, ws_wvT, query, w_q, ws_q,
                       pa, conv_w, conv_b, w_u, ws_le);
    hipLaunchKernelGGL(gemm_score_kernel, dim3(2048), dim3(512), 0, stream,
                       key_in, ws_wvT, ws_le, ws_q, bias, score_w, score_b, align_out);
    hipLaunchKernelGGL(softmax_kernel, dim3(128), dim3(256), 0, stream, align_out);
    hipLaunchKernelGGL(ctx_partial_kernel, dim3(32, 128), dim3(256), 0, stream, value, align_out, ws_pctx);
    hipLaunchKernelGGL(ctx_reduce_kernel, dim3(128), dim3(128), 0, stream, ws_pctx, ctx_out);
}

// Round 18
// 286.905 us; speedup vs baseline: 1.5068x; 1.0379x over previous
//
#include <hip/hip_runtime.h>
#include <hip/hip_bf16.h>
#include <cstdint>

typedef __attribute__((ext_vector_type(8))) short bf16x8;
typedef __attribute__((ext_vector_type(4))) float f32x4;
typedef __attribute__((ext_vector_type(8))) unsigned short u16x8;
typedef __attribute__((ext_vector_type(4))) unsigned int u32x4;

__device__ __forceinline__ unsigned short f2bf(float f) {
    unsigned int u = __float_as_uint(f);
    unsigned int r = (u + 0x7fffu + ((u >> 16) & 1u)) >> 16;
    return (unsigned short)r;
}

__device__ __forceinline__ float tanh_fast(float x) {
    return 1.0f - 2.0f / (__expf(2.0f * x) + 1.0f);
}

#define GLDS(SRC, DST) __builtin_amdgcn_global_load_lds(                         \
        (const __attribute__((address_space(1))) void*)(SRC),                    \
        (__attribute__((address_space(3))) void*)(DST), 16, 0, 0)

// ---------- K0: fused prep: wv_tile (0..255) | qproj (256..383) |
//                loc_le (384..895) | ctx-zero (896) ----------
__global__ __launch_bounds__(256) void prep_kernel(
        const float* __restrict__ wv, unsigned short* __restrict__ wvT,
        const float* __restrict__ query, const float* __restrict__ w_q,
        float* __restrict__ ws_q,
        const float* __restrict__ pa, const float* __restrict__ conv_w,
        const float* __restrict__ conv_b, const float* __restrict__ w_u,
        float* __restrict__ le, float* __restrict__ ctx_out) {
    __shared__ __align__(16) char smem[16640];
    const int bid = blockIdx.x;
    const int t = threadIdx.x;

    if (bid < 256) {
        // ---- wv -> bf16 fragment-tiled B (per head, BK=32 layout) ----
        float (*tile)[129] = reinterpret_cast<float(*)[129]>(smem);
        const int h = bid >> 5, kt = bid & 31;
        for (int i = t; i < 1024; i += 256) {
            const int fl = i >> 5;
            const int e4 = (i & 31) * 4;
            const float4 v = *reinterpret_cast<const float4*>(
                wv + (size_t)(kt * 32 + fl) * 1024 + h * 128 + e4);
            tile[fl][e4 + 0] = v.x; tile[fl][e4 + 1] = v.y;
            tile[fl][e4 + 2] = v.z; tile[fl][e4 + 3] = v.w;
        }
        __syncthreads();
#pragma unroll
        for (int cc2 = 0; cc2 < 2; ++cc2) {
            const int c = cc2 * 256 + t;
            const int cb = c >> 6, kg = (c >> 4) & 3, ccl = c & 15;
            const int e_local = cb * 16 + ccl;
            u16x8 u;
#pragma unroll
            for (int jj = 0; jj < 8; ++jj) u[jj] = f2bf(tile[kg * 8 + jj][e_local]);
            *reinterpret_cast<u16x8*>(wvT + (((size_t)h * 32 + kt) * 512 + c) * 8) = u;
        }
    } else if (bid < 384) {
        // ---- q projection: one (b,h) per block ----
        float* qs = reinterpret_cast<float*>(smem);
        const int bh = bid - 256;
        const int b = bh >> 3, h = bh & 7;
        for (int i = t; i < 1024; i += 256) qs[i] = query[(size_t)b * 1024 + i];
        __syncthreads();
        if (t < 128) {
            float acc = 0.f;
            const float* wcol = w_q + h * 128 + t;
            for (int f = 0; f < 1024; ++f) acc = fmaf(qs[f], wcol[(size_t)f * 1024], acc);
            ws_q[(size_t)bh * 128 + t] = acc;
        }
    } else if (bid < 896) {
        // ---- fused conv1d + location-energy ----
        float* pas = reinterpret_cast<float*>(smem);            // 8*132
        float* wu_s = pas + 1056;                               // 10*128
        float* cw = wu_s + 1280;                                // 240
        float* cb = cw + 240;                                   // 16
        const int idx = bid - 384;
        const int b = idx >> 5, k0 = (idx & 31) * 128;
        for (int i = t; i < 8 * 130; i += 256) {
            const int hh = i / 130, kk = i % 130;
            const int gk = k0 + kk - 1;
            pas[hh * 132 + kk] = (gk >= 0 && gk < 4096)
                ? pa[((size_t)(b * 8 + hh)) * 4096 + gk] : 0.f;
        }
        for (int i = t; i < 1280; i += 256) wu_s[i] = w_u[i];
        if (t < 240) cw[t] = conv_w[t];
        if (t < 10) cb[t] = conv_b[t];
        __syncthreads();
        const int k = t >> 1;
        const int d0 = (t & 1) * 64;
        float lc[10];
#pragma unroll
        for (int c = 0; c < 10; ++c) {
            float acc = cb[c];
#pragma unroll
            for (int hh = 0; hh < 8; ++hh) {
                acc += pas[hh * 132 + k] * cw[(c * 8 + hh) * 3 + 0]
                     + pas[hh * 132 + k + 1] * cw[(c * 8 + hh) * 3 + 1]
                     + pas[hh * 132 + k + 2] * cw[(c * 8 + hh) * 3 + 2];
            }
            lc[c] = acc;
        }
        float* dst = le + ((size_t)(b * 4096) + k0 + k) * 128 + d0;
#pragma unroll
        for (int dd = 0; dd < 64; dd += 4) {
            float4 o;
#pragma unroll
            for (int jj = 0; jj < 4; ++jj) {
                float s = 0.f;
#pragma unroll
                for (int c = 0; c < 10; ++c) s += lc[c] * wu_s[c * 128 + d0 + dd + jj];
                ((float*)&o)[jj] = tanh_fast(s);
            }
            *reinterpret_cast<float4*>(dst + dd) = o;
        }
    } else {
        // ---- zero the 16384-float context region for atomic accumulation ----
        float4 z = {0.f, 0.f, 0.f, 0.f};
        for (int i = t; i < 4096; i += 256)
            *reinterpret_cast<float4*>(ctx_out + (size_t)i * 4) = z;
    }
}

// ---------- K3: GEMM, ring-3 LDS, one barrier/kt (r16 schedule) ----------
// BM=128, BN=256 (2 heads), BK=32; 512 thr, 8 waves (2M x 4N), wave 64x64.
// A: fp32 coalesced -> regs -> cvt_pk -> XOR-swizzled ds_write.
// B: pre-tiled bf16 via GLDS, 1 kt ahead, issued BEFORE the barrier. Ring-3
// makes re-write distance 3 kts -> no end-of-kt barrier; B(kt) certified by
// WRITEA's compiler-inserted vmcnt (A-regs newer than B(kt) in VMEM queue).
#define NT 32
__global__ __launch_bounds__(512) void gemm_score_kernel(
        const float* __restrict__ key_in, const unsigned short* __restrict__ wvT_tiled,
        const float* __restrict__ le,
        const float* __restrict__ ws_q, const float* __restrict__ bias,
        const float* __restrict__ score_w, const float* __restrict__ score_b,
        float* __restrict__ align_out) {
    __shared__ __align__(16) unsigned short As[3][4096];    // 24 KB
    __shared__ __align__(16) unsigned short Bs[3][8192];    // 48 KB
    __shared__ float qb_sm[256], sw_sm[128];
    __shared__ float partial[128][4];

    const int t = threadIdx.x;
    const int lane = t & 63, wid = t >> 6;
    const int wm = wid >> 2;          // 0..1 : M-half
    const int wn = wid & 3;           // 0..3 : (head, d-half)

    // XCD swizzle: the 4 head-pair blocks of one panel adjacent on one XCD
    const int fid = blockIdx.x;       // 0..2047
    const int x = fid & 7, j = fid >> 3;     // j: 0..255
    const int bm = x * 64 + (j >> 2);        // panel 0..511 (128 rows)
    const int hp = j & 3;                    // head-pair 0..3
    const int b = bm >> 5;
    const int kk0 = (bm & 31) << 7;

    if (t < 256) {
        const int hh = t >> 7, d = t & 127;
        qb_sm[t] = ws_q[(size_t)(b * 8 + hp * 2 + hh) * 128 + d] + bias[d];
        if (t < 128) sw_sm[t] = score_w[t];
    }

    // ---- A staging: thread t reads row r_=t>>2, kseg ks=t&3 (coalesced 128B/4 lanes)
    const int r_ = t >> 2, ks = t & 3;
    const float* aRow = key_in + ((size_t)(b * 4096 + kk0) + r_) * 1024 + ks * 8;
    const int cW = (t >> 6) * 64 + ks * 16 + (r_ & 15);
    const int dst0 = (cW ^ (ks | ((ks & 1) << 2))) * 8;            // ushort idx

    // fragment-read lane swizzle (same involution): kg = lane>>4
    const int kgR = lane >> 4;
    const int laneSwz = lane ^ (kgR | ((kgR & 1) << 2));

    // ---- B staging: thread stages two 16B chunks of one head ----
    const unsigned short* bT = wvT_tiled
        + (size_t)(hp * 2 + (t >> 8)) * 131072 + (t & 255) * 8;
    const int dstB = (t >> 8) * 4096 + (t & 255) * 8;              // ushort idx

    float4 st0, st1;

#define LOADA(KT) {                                                               \
        const float* p_ = aRow + (KT) * 32;                                       \
        st0 = *reinterpret_cast<const float4*>(p_);                               \
        st1 = *reinterpret_cast<const float4*>(p_ + 4); }

#define WRITEA(BUF) {                                                             \
        __hip_bfloat162 h0_ = __float22bfloat162_rn({st0.x, st0.y});              \
        __hip_bfloat162 h1_ = __float22bfloat162_rn({st0.z, st0.w});              \
        __hip_bfloat162 h2_ = __float22bfloat162_rn({st1.x, st1.y});              \
        __hip_bfloat162 h3_ = __float22bfloat162_rn({st1.z, st1.w});              \
        u32x4 u_;                                                                 \
        u_[0] = *reinterpret_cast<unsigned int*>(&h0_);                           \
        u_[1] = *reinterpret_cast<unsigned int*>(&h1_);                           \
        u_[2] = *reinterpret_cast<unsigned int*>(&h2_);                           \
        u_[3] = *reinterpret_cast<unsigned int*>(&h3_);                           \
        *reinterpret_cast<u32x4*>(&As[BUF][dst0]) = u_; }

#define STAGE_B(BUF, KT) {                                                        \
        GLDS(bT + (size_t)(KT) * 4096, &Bs[BUF][dstB]);                           \
        GLDS(bT + (size_t)(KT) * 4096 + 2048, &Bs[BUF][dstB + 2048]); }

    f32x4 acc[4][4] = {};

    // prologue: B(0)->buf0, A(0)->buf0 (regs->LDS), preload A(1)
    LOADA(0);
    STAGE_B(0, 0);
    WRITEA(0);
    LOADA(1);

    for (int kt = 0; kt < NT; ++kt) {
        const int cur = kt % 3;
        const int nxt = (kt + 1) % 3;
        STAGE_B(nxt, (kt + 1) & (NT - 1));   // wraps harmlessly on last iter
        WRITEA(nxt);        // regs A(kt+1); implicit vmcnt also certifies B(kt)
        LOADA((kt + 2) & (NT - 1));
        asm volatile("s_waitcnt lgkmcnt(0)\n\t"
                     "s_barrier" ::: "memory");

        bf16x8 af[4], bg[4];
#pragma unroll
        for (int mf = 0; mf < 4; ++mf)
            af[mf] = *reinterpret_cast<const bf16x8*>(
                &As[cur][((wm * 4 + mf) * 64 + laneSwz) * 8]);
#pragma unroll
        for (int nf = 0; nf < 4; ++nf)
            bg[nf] = *reinterpret_cast<const bf16x8*>(
                &Bs[cur][(wn >> 1) * 4096 + ((wn & 1) * 4 + nf) * 512 + lane * 8]);
        __builtin_amdgcn_s_setprio(1);
#pragma unroll
        for (int mf = 0; mf < 4; ++mf)
#pragma unroll
            for (int nf = 0; nf < 4; ++nf)
                acc[mf][nf] = __builtin_amdgcn_mfma_f32_16x16x32_bf16(
                    af[mf], bg[nf], acc[mf][nf], 0, 0, 0);
        __builtin_amdgcn_s_setprio(0);
        // no end-of-kt barrier: ring-3 re-write distance covers the hazard
    }

    // ---- epilogue: score = sum_d tanh(kproj + q + bias + le) * sw ----
    const float K2 = 2.8853900817779268f;
    const float sb = score_b[0];
    const int g = lane >> 4;
    const int l15 = lane & 15;
    float kqb[4], swv[4];
#pragma unroll
    for (int nf = 0; nf < 4; ++nf) {
        const int d128 = (wn & 1) * 64 + nf * 16 + l15;
        kqb[nf] = qb_sm[(wn >> 1) * 128 + d128] * K2;
        swv[nf] = sw_sm[d128];
    }
    const float* leB = le + ((size_t)(b * 4096 + kk0) + wm * 64 + g * 4) * 128
                       + (wn & 1) * 64 + l15;

#pragma unroll
    for (int mf = 0; mf < 4; ++mf) {
        float lv[16];
#pragma unroll
        for (int jj = 0; jj < 4; ++jj)
#pragma unroll
            for (int nf = 0; nf < 4; ++nf)
                lv[jj * 4 + nf] = leB[(size_t)(mf * 16 + jj) * 128 + nf * 16];
#pragma unroll
        for (int jj = 0; jj < 4; ++jj) {
            const int row_l = wm * 64 + mf * 16 + g * 4 + jj;
            float sum = 0.f;
#pragma unroll
            for (int nf = 0; nf < 4; ++nf) {
                const float m = fmaf(K2, lv[jj * 4 + nf], kqb[nf]);
                const float tt = fmaf(K2, acc[mf][nf][jj], m);
                const float y = __builtin_amdgcn_exp2f(tt);
                const float r = fmaf(-2.0f, __builtin_amdgcn_rcpf(y + 1.0f), 1.0f);
                sum = fmaf(r, swv[nf], sum);
            }
            sum += __shfl_xor(sum, 1);
            sum += __shfl_xor(sum, 2);
            sum += __shfl_xor(sum, 4);
            sum += __shfl_xor(sum, 8);
            if (l15 == 0) partial[row_l][wn] = sum;
        }
    }
    __syncthreads();
    if (t < 256) {
        const int r = t >> 1, hh = t & 1;
        const float sc = partial[r][hh * 2] + partial[r][hh * 2 + 1] + sb;
        align_out[(size_t)(b * 8 + hp * 2 + hh) * 4096 + kk0 + r] = sc;
    }
}

// ---------- K4: softmax over k ----------
__global__ __launch_bounds__(256) void softmax_kernel(float* __restrict__ align_o) {
    const int bh = blockIdx.x;
    float* row = align_o + (size_t)bh * 4096;
    const int t = threadIdx.x;
    float v[16];
    float m = -1e30f;
#pragma unroll
    for (int i = 0; i < 16; ++i) {
        v[i] = row[i * 256 + t];
        m = fmaxf(m, v[i]);
    }
#pragma unroll
    for (int off = 32; off; off >>= 1) m = fmaxf(m, __shfl_xor(m, off));
    __shared__ float sm[4], ss[4];
    const int wid = t >> 6;
    if ((t & 63) == 0) sm[wid] = m;
    __syncthreads();
    m = fmaxf(fmaxf(sm[0], sm[1]), fmaxf(sm[2], sm[3]));
    float s = 0.f;
#pragma unroll
    for (int i = 0; i < 16; ++i) {
        v[i] = __expf(v[i] - m);
        s += v[i];
    }
#pragma unroll
    for (int off = 32; off; off >>= 1) s += __shfl_xor(s, off);
    if ((t & 63) == 0) ss[wid] = s;
    __syncthreads();
    s = ss[0] + ss[1] + ss[2] + ss[3];
    const float inv = 1.f / s;
#pragma unroll
    for (int i = 0; i < 16; ++i) row[i * 256 + t] = v[i] * inv;
}

// ---------- K5: split-K context partials + atomic reduce ----------
__global__ __launch_bounds__(256) void ctx_partial_kernel(
        const float* __restrict__ value, const float* __restrict__ align_o,
        float* __restrict__ ctx_out) {
    const int s = blockIdx.x;    // 0..31
    const int bh = blockIdx.y;   // 0..127
    const int b = bh >> 3, h = bh & 7;
    const int t = threadIdx.x;
    const int d4 = (t & 31) * 4;
    const int kg = t >> 5;
    const float* arow = align_o + (size_t)bh * 4096 + s * 128;
    const float* vbase = value + ((size_t)(b * 4096 + s * 128)) * 1024 + h * 128 + d4;
    float4 acc = {0.f, 0.f, 0.f, 0.f};
    for (int i = 0; i < 16; ++i) {
        const int kk = i * 8 + kg;
        const float a = arow[kk];
        const float4 v = *reinterpret_cast<const float4*>(vbase + (size_t)kk * 1024);
        acc.x += a * v.x; acc.y += a * v.y; acc.z += a * v.z; acc.w += a * v.w;
    }
    __shared__ float sm2[8][128];
    *reinterpret_cast<float4*>(&sm2[kg][d4]) = acc;
    __syncthreads();
    if (t < 128) {
        float s0 = 0.f;
#pragma unroll
        for (int gg = 0; gg < 8; ++gg) s0 += sm2[gg][t];
        atomicAdd(&ctx_out[(size_t)bh * 128 + t], s0);
    }
}

extern "C" void kernel_launch(void* const* d_in, const int* in_sizes, int n_in,
                              void* d_out, int out_size, void* d_ws, size_t ws_size,
                              hipStream_t stream) {
    const float* query   = (const float*)d_in[0];
    const float* key_in  = (const float*)d_in[1];
    const float* value   = (const float*)d_in[2];
    const float* pa      = (const float*)d_in[3];
    const float* conv_w  = (const float*)d_in[4];
    const float* conv_b  = (const float*)d_in[5];
    const float* w_u     = (const float*)d_in[6];
    const float* w_q     = (const float*)d_in[7];
    const float* w_v     = (const float*)d_in[8];
    const float* bias    = (const float*)d_in[9];
    const float* score_w = (const float*)d_in[10];
    const float* score_b = (const float*)d_in[11];

    float* out = (float*)d_out;
    float* ctx_out = out;                 // [128,128]
    float* align_out = out + 16384;       // [16,8,4096]

    char* ws = (char*)d_ws;
    const size_t OFF_Q    = 0;                        // 64 KB
    const size_t OFF_WVT  = 65536;                    // 2 MB (tiled bf16)
    const size_t OFF_LE   = OFF_WVT + 2097152;        // 33.55 MB

    float* ws_q            = (float*)(ws + OFF_Q);
    unsigned short* ws_wvT = (unsigned short*)(ws + OFF_WVT);
    float* ws_le           = (float*)(ws + OFF_LE);

    hipLaunchKernelGGL(prep_kernel, dim3(897), dim3(256), 0, stream,
                       w_v, ws_wvT, query, w_q, ws_q,
                       pa, conv_w, conv_b, w_u, ws_le, ctx_out);
    hipLaunchKernelGGL(gemm_score_kernel, dim3(2048), dim3(512), 0, stream,
                       key_in, ws_wvT, ws_le, ws_q, bias, score_w, score_b, align_out);
    hipLaunchKernelGGL(softmax_kernel, dim3(128), dim3(256), 0, stream, align_out);
    hipLaunchKernelGGL(ctx_partial_kernel, dim3(32, 128), dim3(256), 0, stream,
                       value, align_out, ctx_out);
}

// Round 19
// 285.726 us; speedup vs baseline: 1.5130x; 1.0041x over previous
//
#include <hip/hip_runtime.h>
#include <hip/hip_bf16.h>
#include <cstdint>

typedef __attribute__((ext_vector_type(8))) short bf16x8;
typedef __attribute__((ext_vector_type(4))) float f32x4;
typedef __attribute__((ext_vector_type(8))) unsigned short u16x8;
typedef __attribute__((ext_vector_type(4))) unsigned int u32x4;

__device__ __forceinline__ unsigned short f2bf(float f) {
    unsigned int u = __float_as_uint(f);
    unsigned int r = (u + 0x7fffu + ((u >> 16) & 1u)) >> 16;
    return (unsigned short)r;
}

__device__ __forceinline__ float tanh_fast(float x) {
    return 1.0f - 2.0f / (__expf(2.0f * x) + 1.0f);
}

#define GLDS(SRC, DST) __builtin_amdgcn_global_load_lds(                         \
        (const __attribute__((address_space(1))) void*)(SRC),                    \
        (__attribute__((address_space(3))) void*)(DST), 16, 0, 0)

// ---------- K0: fused prep: wv_tile (0..255) | qproj (256..383) |
//                loc_le (384..895) | ctx+rowsum zero (896) ----------
__global__ __launch_bounds__(256) void prep_kernel(
        const float* __restrict__ wv, unsigned short* __restrict__ wvT,
        const float* __restrict__ query, const float* __restrict__ w_q,
        float* __restrict__ ws_q,
        const float* __restrict__ pa, const float* __restrict__ conv_w,
        const float* __restrict__ conv_b, const float* __restrict__ w_u,
        float* __restrict__ le, float* __restrict__ ctx_out,
        float* __restrict__ rowsum) {
    __shared__ __align__(16) char smem[16640];
    const int bid = blockIdx.x;
    const int t = threadIdx.x;

    if (bid < 256) {
        // ---- wv -> bf16 fragment-tiled B (per head, BK=32 layout) ----
        float (*tile)[129] = reinterpret_cast<float(*)[129]>(smem);
        const int h = bid >> 5, kt = bid & 31;
        for (int i = t; i < 1024; i += 256) {
            const int fl = i >> 5;
            const int e4 = (i & 31) * 4;
            const float4 v = *reinterpret_cast<const float4*>(
                wv + (size_t)(kt * 32 + fl) * 1024 + h * 128 + e4);
            tile[fl][e4 + 0] = v.x; tile[fl][e4 + 1] = v.y;
            tile[fl][e4 + 2] = v.z; tile[fl][e4 + 3] = v.w;
        }
        __syncthreads();
#pragma unroll
        for (int cc2 = 0; cc2 < 2; ++cc2) {
            const int c = cc2 * 256 + t;
            const int cb = c >> 6, kg = (c >> 4) & 3, ccl = c & 15;
            const int e_local = cb * 16 + ccl;
            u16x8 u;
#pragma unroll
            for (int jj = 0; jj < 8; ++jj) u[jj] = f2bf(tile[kg * 8 + jj][e_local]);
            *reinterpret_cast<u16x8*>(wvT + (((size_t)h * 32 + kt) * 512 + c) * 8) = u;
        }
    } else if (bid < 384) {
        // ---- q projection: one (b,h) per block ----
        float* qs = reinterpret_cast<float*>(smem);
        const int bh = bid - 256;
        const int b = bh >> 3, h = bh & 7;
        for (int i = t; i < 1024; i += 256) qs[i] = query[(size_t)b * 1024 + i];
        __syncthreads();
        if (t < 128) {
            float acc = 0.f;
            const float* wcol = w_q + h * 128 + t;
            for (int f = 0; f < 1024; ++f) acc = fmaf(qs[f], wcol[(size_t)f * 1024], acc);
            ws_q[(size_t)bh * 128 + t] = acc;
        }
    } else if (bid < 896) {
        // ---- fused conv1d + location-energy ----
        float* pas = reinterpret_cast<float*>(smem);            // 8*132
        float* wu_s = pas + 1056;                               // 10*128
        float* cw = wu_s + 1280;                                // 240
        float* cb = cw + 240;                                   // 16
        const int idx = bid - 384;
        const int b = idx >> 5, k0 = (idx & 31) * 128;
        for (int i = t; i < 8 * 130; i += 256) {
            const int hh = i / 130, kk = i % 130;
            const int gk = k0 + kk - 1;
            pas[hh * 132 + kk] = (gk >= 0 && gk < 4096)
                ? pa[((size_t)(b * 8 + hh)) * 4096 + gk] : 0.f;
        }
        for (int i = t; i < 1280; i += 256) wu_s[i] = w_u[i];
        if (t < 240) cw[t] = conv_w[t];
        if (t < 10) cb[t] = conv_b[t];
        __syncthreads();
        const int k = t >> 1;
        const int d0 = (t & 1) * 64;
        float lc[10];
#pragma unroll
        for (int c = 0; c < 10; ++c) {
            float acc = cb[c];
#pragma unroll
            for (int hh = 0; hh < 8; ++hh) {
                acc += pas[hh * 132 + k] * cw[(c * 8 + hh) * 3 + 0]
                     + pas[hh * 132 + k + 1] * cw[(c * 8 + hh) * 3 + 1]
                     + pas[hh * 132 + k + 2] * cw[(c * 8 + hh) * 3 + 2];
            }
            lc[c] = acc;
        }
        float* dst = le + ((size_t)(b * 4096) + k0 + k) * 128 + d0;
#pragma unroll
        for (int dd = 0; dd < 64; dd += 4) {
            float4 o;
#pragma unroll
            for (int jj = 0; jj < 4; ++jj) {
                float s = 0.f;
#pragma unroll
                for (int c = 0; c < 10; ++c) s += lc[c] * wu_s[c * 128 + d0 + dd + jj];
                ((float*)&o)[jj] = tanh_fast(s);
            }
            *reinterpret_cast<float4*>(dst + dd) = o;
        }
    } else {
        // ---- zero context (16384 floats) + rowsum (128 floats) ----
        float4 z = {0.f, 0.f, 0.f, 0.f};
        for (int i = t; i < 4096; i += 256)
            *reinterpret_cast<float4*>(ctx_out + (size_t)i * 4) = z;
        if (t < 128) rowsum[t] = 0.f;
    }
}

// ---------- K3: GEMM, ring-3 LDS, one barrier/kt + fused exp-softmax ----------
// BM=128, BN=256 (2 heads), BK=32; 512 thr, 8 waves (2M x 4N), wave 64x64.
// A: fp32 coalesced -> regs -> cvt_pk -> XOR-swizzled ds_write.
// B: pre-tiled bf16 via GLDS, 1 kt ahead, issued BEFORE the barrier. Ring-3
// makes re-write distance 3 kts -> no end-of-kt barrier. Epilogue writes
// exp(score) (safe: |score|<~5) and atomic-accumulates per-head row sums.
#define NT 32
__global__ __launch_bounds__(512) void gemm_score_kernel(
        const float* __restrict__ key_in, const unsigned short* __restrict__ wvT_tiled,
        const float* __restrict__ le,
        const float* __restrict__ ws_q, const float* __restrict__ bias,
        const float* __restrict__ score_w, const float* __restrict__ score_b,
        float* __restrict__ align_out, float* __restrict__ rowsum) {
    __shared__ __align__(16) unsigned short As[3][4096];    // 24 KB
    __shared__ __align__(16) unsigned short Bs[3][8192];    // 48 KB
    __shared__ float qb_sm[256], sw_sm[128];
    __shared__ float partial[128][4];

    const int t = threadIdx.x;
    const int lane = t & 63, wid = t >> 6;
    const int wm = wid >> 2;          // 0..1 : M-half
    const int wn = wid & 3;           // 0..3 : (head, d-half)

    // XCD swizzle: the 4 head-pair blocks of one panel adjacent on one XCD
    const int fid = blockIdx.x;       // 0..2047
    const int x = fid & 7, j = fid >> 3;     // j: 0..255
    const int bm = x * 64 + (j >> 2);        // panel 0..511 (128 rows)
    const int hp = j & 3;                    // head-pair 0..3
    const int b = bm >> 5;
    const int kk0 = (bm & 31) << 7;

    if (t < 256) {
        const int hh = t >> 7, d = t & 127;
        qb_sm[t] = ws_q[(size_t)(b * 8 + hp * 2 + hh) * 128 + d] + bias[d];
        if (t < 128) sw_sm[t] = score_w[t];
    }

    // ---- A staging: thread t reads row r_=t>>2, kseg ks=t&3 (coalesced 128B/4 lanes)
    const int r_ = t >> 2, ks = t & 3;
    const float* aRow = key_in + ((size_t)(b * 4096 + kk0) + r_) * 1024 + ks * 8;
    const int cW = (t >> 6) * 64 + ks * 16 + (r_ & 15);
    const int dst0 = (cW ^ (ks | ((ks & 1) << 2))) * 8;            // ushort idx

    // fragment-read lane swizzle (same involution): kg = lane>>4
    const int kgR = lane >> 4;
    const int laneSwz = lane ^ (kgR | ((kgR & 1) << 2));

    // ---- B staging: thread stages two 16B chunks of one head ----
    const unsigned short* bT = wvT_tiled
        + (size_t)(hp * 2 + (t >> 8)) * 131072 + (t & 255) * 8;
    const int dstB = (t >> 8) * 4096 + (t & 255) * 8;              // ushort idx

    float4 st0, st1;

#define LOADA(KT) {                                                               \
        const float* p_ = aRow + (KT) * 32;                                       \
        st0 = *reinterpret_cast<const float4*>(p_);                               \
        st1 = *reinterpret_cast<const float4*>(p_ + 4); }

#define WRITEA(BUF) {                                                             \
        __hip_bfloat162 h0_ = __float22bfloat162_rn({st0.x, st0.y});              \
        __hip_bfloat162 h1_ = __float22bfloat162_rn({st0.z, st0.w});              \
        __hip_bfloat162 h2_ = __float22bfloat162_rn({st1.x, st1.y});              \
        __hip_bfloat162 h3_ = __float22bfloat162_rn({st1.z, st1.w});              \
        u32x4 u_;                                                                 \
        u_[0] = *reinterpret_cast<unsigned int*>(&h0_);                           \
        u_[1] = *reinterpret_cast<unsigned int*>(&h1_);                           \
        u_[2] = *reinterpret_cast<unsigned int*>(&h2_);                           \
        u_[3] = *reinterpret_cast<unsigned int*>(&h3_);                           \
        *reinterpret_cast<u32x4*>(&As[BUF][dst0]) = u_; }

#define STAGE_B(BUF, KT) {                                                        \
        GLDS(bT + (size_t)(KT) * 4096, &Bs[BUF][dstB]);                           \
        GLDS(bT + (size_t)(KT) * 4096 + 2048, &Bs[BUF][dstB + 2048]); }

    f32x4 acc[4][4] = {};

    // prologue: B(0)->buf0, A(0)->buf0 (regs->LDS), preload A(1)
    LOADA(0);
    STAGE_B(0, 0);
    WRITEA(0);
    LOADA(1);

    for (int kt = 0; kt < NT; ++kt) {
        const int cur = kt % 3;
        const int nxt = (kt + 1) % 3;
        STAGE_B(nxt, (kt + 1) & (NT - 1));   // wraps harmlessly on last iter
        WRITEA(nxt);        // regs A(kt+1); implicit vmcnt also certifies B(kt)
        LOADA((kt + 2) & (NT - 1));
        asm volatile("s_waitcnt lgkmcnt(0)\n\t"
                     "s_barrier" ::: "memory");

        bf16x8 af[4], bg[4];
#pragma unroll
        for (int mf = 0; mf < 4; ++mf)
            af[mf] = *reinterpret_cast<const bf16x8*>(
                &As[cur][((wm * 4 + mf) * 64 + laneSwz) * 8]);
#pragma unroll
        for (int nf = 0; nf < 4; ++nf)
            bg[nf] = *reinterpret_cast<const bf16x8*>(
                &Bs[cur][(wn >> 1) * 4096 + ((wn & 1) * 4 + nf) * 512 + lane * 8]);
        __builtin_amdgcn_s_setprio(1);
#pragma unroll
        for (int mf = 0; mf < 4; ++mf)
#pragma unroll
            for (int nf = 0; nf < 4; ++nf)
                acc[mf][nf] = __builtin_amdgcn_mfma_f32_16x16x32_bf16(
                    af[mf], bg[nf], acc[mf][nf], 0, 0, 0);
        __builtin_amdgcn_s_setprio(0);
        // no end-of-kt barrier: ring-3 re-write distance covers the hazard
    }

    // ---- epilogue: score = sum_d tanh(kproj+q+bias+le)*sw; write exp(score) ----
    const float K2 = 2.8853900817779268f;
    const float LOG2E = 1.4426950408889634f;
    const float sb = score_b[0];
    const int g = lane >> 4;
    const int l15 = lane & 15;
    float kqb[4], swv[4];
#pragma unroll
    for (int nf = 0; nf < 4; ++nf) {
        const int d128 = (wn & 1) * 64 + nf * 16 + l15;
        kqb[nf] = qb_sm[(wn >> 1) * 128 + d128] * K2;
        swv[nf] = sw_sm[d128];
    }
    const float* leB = le + ((size_t)(b * 4096 + kk0) + wm * 64 + g * 4) * 128
                       + (wn & 1) * 64 + l15;

#pragma unroll
    for (int mf = 0; mf < 4; ++mf) {
        float lv[16];
#pragma unroll
        for (int jj = 0; jj < 4; ++jj)
#pragma unroll
            for (int nf = 0; nf < 4; ++nf)
                lv[jj * 4 + nf] = leB[(size_t)(mf * 16 + jj) * 128 + nf * 16];
#pragma unroll
        for (int jj = 0; jj < 4; ++jj) {
            const int row_l = wm * 64 + mf * 16 + g * 4 + jj;
            float sum = 0.f;
#pragma unroll
            for (int nf = 0; nf < 4; ++nf) {
                const float m = fmaf(K2, lv[jj * 4 + nf], kqb[nf]);
                const float tt = fmaf(K2, acc[mf][nf][jj], m);
                const float y = __builtin_amdgcn_exp2f(tt);
                const float r = fmaf(-2.0f, __builtin_amdgcn_rcpf(y + 1.0f), 1.0f);
                sum = fmaf(r, swv[nf], sum);
            }
            sum += __shfl_xor(sum, 1);
            sum += __shfl_xor(sum, 2);
            sum += __shfl_xor(sum, 4);
            sum += __shfl_xor(sum, 8);
            if (l15 == 0) partial[row_l][wn] = sum;
        }
    }
    __syncthreads();
    if (t < 256) {
        const int r = t >> 1, hh = t & 1;
        const float sc = partial[r][hh * 2] + partial[r][hh * 2 + 1] + sb;
        const float e = __builtin_amdgcn_exp2f(sc * LOG2E);
        align_out[(size_t)(b * 8 + hp * 2 + hh) * 4096 + kk0 + r] = e;
        // reduce e over the wave's 32 rows (hh parity preserved by stride>=2)
        float s = e;
        s += __shfl_xor(s, 2);
        s += __shfl_xor(s, 4);
        s += __shfl_xor(s, 8);
        s += __shfl_xor(s, 16);
        s += __shfl_xor(s, 32);
        if ((lane >> 1) == 0)     // lanes 0 (hh=0) and 1 (hh=1)
            atomicAdd(&rowsum[b * 8 + hp * 2 + hh], s);
    }
}

// ---------- K5: context partials (exp-normalized) + atomic reduce +
//               in-place align normalization ----------
__global__ __launch_bounds__(256) void ctx_partial_kernel(
        const float* __restrict__ value, float* __restrict__ align_o,
        const float* __restrict__ rowsum, float* __restrict__ ctx_out) {
    const int s = blockIdx.x;    // 0..31
    const int bh = blockIdx.y;   // 0..127
    const int b = bh >> 3, h = bh & 7;
    const int t = threadIdx.x;
    const int d4 = (t & 31) * 4;
    const int kg = t >> 5;
    const float inv = 1.0f / rowsum[bh];
    float* arow = align_o + (size_t)bh * 4096 + s * 128;
    const float* vbase = value + ((size_t)(b * 4096 + s * 128)) * 1024 + h * 128 + d4;
    float4 acc = {0.f, 0.f, 0.f, 0.f};
    for (int i = 0; i < 16; ++i) {
        const int kk = i * 8 + kg;
        const float a = arow[kk];
        const float4 v = *reinterpret_cast<const float4*>(vbase + (size_t)kk * 1024);
        acc.x += a * v.x; acc.y += a * v.y; acc.z += a * v.z; acc.w += a * v.w;
    }
    __shared__ float sm2[8][128];
    *reinterpret_cast<float4*>(&sm2[kg][d4]) = acc;
    __syncthreads();                       // all raw reads of arow complete
    if (t < 128) {
        float s0 = 0.f;
#pragma unroll
        for (int gg = 0; gg < 8; ++gg) s0 += sm2[gg][t];
        atomicAdd(&ctx_out[(size_t)bh * 128 + t], s0 * inv);
        arow[t] *= inv;                    // normalize this block's align chunk
    }
}

extern "C" void kernel_launch(void* const* d_in, const int* in_sizes, int n_in,
                              void* d_out, int out_size, void* d_ws, size_t ws_size,
                              hipStream_t stream) {
    const float* query   = (const float*)d_in[0];
    const float* key_in  = (const float*)d_in[1];
    const float* value   = (const float*)d_in[2];
    const float* pa      = (const float*)d_in[3];
    const float* conv_w  = (const float*)d_in[4];
    const float* conv_b  = (const float*)d_in[5];
    const float* w_u     = (const float*)d_in[6];
    const float* w_q     = (const float*)d_in[7];
    const float* w_v     = (const float*)d_in[8];
    const float* bias    = (const float*)d_in[9];
    const float* score_w = (const float*)d_in[10];
    const float* score_b = (const float*)d_in[11];

    float* out = (float*)d_out;
    float* ctx_out = out;                 // [128,128]
    float* align_out = out + 16384;       // [16,8,4096]

    char* ws = (char*)d_ws;
    const size_t OFF_Q    = 0;                        // 64 KB
    const size_t OFF_RS   = 65536;                    // 512 B (rowsum)
    const size_t OFF_WVT  = 66048;                    // 2 MB (tiled bf16)
    const size_t OFF_LE   = OFF_WVT + 2097152;        // 33.55 MB

    float* ws_q            = (float*)(ws + OFF_Q);
    float* ws_rs           = (float*)(ws + OFF_RS);
    unsigned short* ws_wvT = (unsigned short*)(ws + OFF_WVT);
    float* ws_le           = (float*)(ws + OFF_LE);

    hipLaunchKernelGGL(prep_kernel, dim3(897), dim3(256), 0, stream,
                       w_v, ws_wvT, query, w_q, ws_q,
                       pa, conv_w, conv_b, w_u, ws_le, ctx_out, ws_rs);
    hipLaunchKernelGGL(gemm_score_kernel, dim3(2048), dim3(512), 0, stream,
                       key_in, ws_wvT, ws_le, ws_q, bias, score_w, score_b,
                       align_out, ws_rs);
    hipLaunchKernelGGL(ctx_partial_kernel, dim3(32, 128), dim3(256), 0, stream,
                       value, align_out, ws_rs, ctx_out);
}

// Round 20
// 272.647 us; speedup vs baseline: 1.5856x; 1.0480x over previous
//
#include <hip/hip_runtime.h>
#include <hip/hip_bf16.h>
#include <cstdint>

typedef __attribute__((ext_vector_type(8))) short bf16x8;
typedef __attribute__((ext_vector_type(4))) float f32x4;
typedef __attribute__((ext_vector_type(8))) unsigned short u16x8;
typedef __attribute__((ext_vector_type(4))) unsigned int u32x4;

__device__ __forceinline__ unsigned short f2bf(float f) {
    unsigned int u = __float_as_uint(f);
    unsigned int r = (u + 0x7fffu + ((u >> 16) & 1u)) >> 16;
    return (unsigned short)r;
}

__device__ __forceinline__ float tanh_fast(float x) {
    return 1.0f - 2.0f / (__expf(2.0f * x) + 1.0f);
}

#define GLDS(SRC, DST) __builtin_amdgcn_global_load_lds(                         \
        (const __attribute__((address_space(1))) void*)(SRC),                    \
        (__attribute__((address_space(3))) void*)(DST), 16, 0, 0)

// ---------- K0: fused prep: wv_tile (0..255) | qproj (256..383) |
//                loc_le (384..895) | ctx+rowsum zero (896) ----------
__global__ __launch_bounds__(256) void prep_kernel(
        const float* __restrict__ wv, unsigned short* __restrict__ wvT,
        const float* __restrict__ query, const float* __restrict__ w_q,
        float* __restrict__ ws_q,
        const float* __restrict__ pa, const float* __restrict__ conv_w,
        const float* __restrict__ conv_b, const float* __restrict__ w_u,
        float* __restrict__ le, float* __restrict__ ctx_out,
        float* __restrict__ rowsum) {
    __shared__ __align__(16) char smem[16640];
    const int bid = blockIdx.x;
    const int t = threadIdx.x;

    if (bid < 256) {
        // ---- wv -> bf16 fragment-tiled B (per head, BK=32 layout) ----
        float (*tile)[129] = reinterpret_cast<float(*)[129]>(smem);
        const int h = bid >> 5, kt = bid & 31;
        for (int i = t; i < 1024; i += 256) {
            const int fl = i >> 5;
            const int e4 = (i & 31) * 4;
            const float4 v = *reinterpret_cast<const float4*>(
                wv + (size_t)(kt * 32 + fl) * 1024 + h * 128 + e4);
            tile[fl][e4 + 0] = v.x; tile[fl][e4 + 1] = v.y;
            tile[fl][e4 + 2] = v.z; tile[fl][e4 + 3] = v.w;
        }
        __syncthreads();
#pragma unroll
        for (int cc2 = 0; cc2 < 2; ++cc2) {
            const int c = cc2 * 256 + t;
            const int cb = c >> 6, kg = (c >> 4) & 3, ccl = c & 15;
            const int e_local = cb * 16 + ccl;
            u16x8 u;
#pragma unroll
            for (int jj = 0; jj < 8; ++jj) u[jj] = f2bf(tile[kg * 8 + jj][e_local]);
            *reinterpret_cast<u16x8*>(wvT + (((size_t)h * 32 + kt) * 512 + c) * 8) = u;
        }
    } else if (bid < 384) {
        // ---- q projection: one (b,h) per block ----
        float* qs = reinterpret_cast<float*>(smem);
        const int bh = bid - 256;
        const int b = bh >> 3, h = bh & 7;
        for (int i = t; i < 1024; i += 256) qs[i] = query[(size_t)b * 1024 + i];
        __syncthreads();
        if (t < 128) {
            float acc = 0.f;
            const float* wcol = w_q + h * 128 + t;
            for (int f = 0; f < 1024; ++f) acc = fmaf(qs[f], wcol[(size_t)f * 1024], acc);
            ws_q[(size_t)bh * 128 + t] = acc;
        }
    } else if (bid < 896) {
        // ---- fused conv1d + location-energy ----
        float* pas = reinterpret_cast<float*>(smem);            // 8*132
        float* wu_s = pas + 1056;                               // 10*128
        float* cw = wu_s + 1280;                                // 240
        float* cb = cw + 240;                                   // 16
        const int idx = bid - 384;
        const int b = idx >> 5, k0 = (idx & 31) * 128;
        for (int i = t; i < 8 * 130; i += 256) {
            const int hh = i / 130, kk = i % 130;
            const int gk = k0 + kk - 1;
            pas[hh * 132 + kk] = (gk >= 0 && gk < 4096)
                ? pa[((size_t)(b * 8 + hh)) * 4096 + gk] : 0.f;
        }
        for (int i = t; i < 1280; i += 256) wu_s[i] = w_u[i];
        if (t < 240) cw[t] = conv_w[t];
        if (t < 10) cb[t] = conv_b[t];
        __syncthreads();
        const int k = t >> 1;
        const int d0 = (t & 1) * 64;
        float lc[10];
#pragma unroll
        for (int c = 0; c < 10; ++c) {
            float acc = cb[c];
#pragma unroll
            for (int hh = 0; hh < 8; ++hh) {
                acc += pas[hh * 132 + k] * cw[(c * 8 + hh) * 3 + 0]
                     + pas[hh * 132 + k + 1] * cw[(c * 8 + hh) * 3 + 1]
                     + pas[hh * 132 + k + 2] * cw[(c * 8 + hh) * 3 + 2];
            }
            lc[c] = acc;
        }
        float* dst = le + ((size_t)(b * 4096) + k0 + k) * 128 + d0;
#pragma unroll
        for (int dd = 0; dd < 64; dd += 4) {
            float4 o;
#pragma unroll
            for (int jj = 0; jj < 4; ++jj) {
                float s = 0.f;
#pragma unroll
                for (int c = 0; c < 10; ++c) s += lc[c] * wu_s[c * 128 + d0 + dd + jj];
                ((float*)&o)[jj] = tanh_fast(s);
            }
            *reinterpret_cast<float4*>(dst + dd) = o;
        }
    } else {
        // ---- zero context (16384 floats) + rowsum (128 floats) ----
        float4 z = {0.f, 0.f, 0.f, 0.f};
        for (int i = t; i < 4096; i += 256)
            *reinterpret_cast<float4*>(ctx_out + (size_t)i * 4) = z;
        if (t < 128) rowsum[t] = 0.f;
    }
}

// ---------- K3: GEMM + exp-score + fused context GEMV ----------
// BM=128, BN=256 (2 heads), BK=32; 512 thr, 8 waves (2M x 4N), wave 64x64.
// Ring-3 LDS, one barrier/kt. Epilogue: writes raw exp(score) to align,
// atomic rowsum, then dots exp-scores with value slice (128KB, coalesced)
// and atomic-accumulates UNNORMALIZED context. finalize_kernel divides.
#define NT 32
__global__ __launch_bounds__(512) void gemm_score_kernel(
        const float* __restrict__ key_in, const unsigned short* __restrict__ wvT_tiled,
        const float* __restrict__ le, const float* __restrict__ value,
        const float* __restrict__ ws_q, const float* __restrict__ bias,
        const float* __restrict__ score_w, const float* __restrict__ score_b,
        float* __restrict__ align_out, float* __restrict__ rowsum,
        float* __restrict__ ctx_out) {
    __shared__ __align__(16) unsigned short As[3][4096];    // 24 KB
    __shared__ __align__(16) unsigned short Bs[3][8192];    // 48 KB
    __shared__ float qb_sm[256], sw_sm[128];
    __shared__ float partial[128][4];                       // reused as comb[512]
    __shared__ float e_sm[256];                             // [hh*128 + r]

    const int t = threadIdx.x;
    const int lane = t & 63, wid = t >> 6;
    const int wm = wid >> 2;          // 0..1 : M-half
    const int wn = wid & 3;           // 0..3 : (head, d-half)

    // XCD swizzle: the 4 head-pair blocks of one panel adjacent on one XCD
    const int fid = blockIdx.x;       // 0..2047
    const int x = fid & 7, j = fid >> 3;     // j: 0..255
    const int bm = x * 64 + (j >> 2);        // panel 0..511 (128 rows)
    const int hp = j & 3;                    // head-pair 0..3
    const int b = bm >> 5;
    const int kk0 = (bm & 31) << 7;

    if (t < 256) {
        const int hh = t >> 7, d = t & 127;
        qb_sm[t] = ws_q[(size_t)(b * 8 + hp * 2 + hh) * 128 + d] + bias[d];
        if (t < 128) sw_sm[t] = score_w[t];
    }

    // ---- A staging: thread t reads row r_=t>>2, kseg ks=t&3 (coalesced 128B/4 lanes)
    const int r_ = t >> 2, ks = t & 3;
    const float* aRow = key_in + ((size_t)(b * 4096 + kk0) + r_) * 1024 + ks * 8;
    const int cW = (t >> 6) * 64 + ks * 16 + (r_ & 15);
    const int dst0 = (cW ^ (ks | ((ks & 1) << 2))) * 8;            // ushort idx

    // fragment-read lane swizzle (same involution): kg = lane>>4
    const int kgR = lane >> 4;
    const int laneSwz = lane ^ (kgR | ((kgR & 1) << 2));

    // ---- B staging: thread stages two 16B chunks of one head ----
    const unsigned short* bT = wvT_tiled
        + (size_t)(hp * 2 + (t >> 8)) * 131072 + (t & 255) * 8;
    const int dstB = (t >> 8) * 4096 + (t & 255) * 8;              // ushort idx

    float4 st0, st1;

#define LOADA(KT) {                                                               \
        const float* p_ = aRow + (KT) * 32;                                       \
        st0 = *reinterpret_cast<const float4*>(p_);                               \
        st1 = *reinterpret_cast<const float4*>(p_ + 4); }

#define WRITEA(BUF) {                                                             \
        __hip_bfloat162 h0_ = __float22bfloat162_rn({st0.x, st0.y});              \
        __hip_bfloat162 h1_ = __float22bfloat162_rn({st0.z, st0.w});              \
        __hip_bfloat162 h2_ = __float22bfloat162_rn({st1.x, st1.y});              \
        __hip_bfloat162 h3_ = __float22bfloat162_rn({st1.z, st1.w});              \
        u32x4 u_;                                                                 \
        u_[0] = *reinterpret_cast<unsigned int*>(&h0_);                           \
        u_[1] = *reinterpret_cast<unsigned int*>(&h1_);                           \
        u_[2] = *reinterpret_cast<unsigned int*>(&h2_);                           \
        u_[3] = *reinterpret_cast<unsigned int*>(&h3_);                           \
        *reinterpret_cast<u32x4*>(&As[BUF][dst0]) = u_; }

#define STAGE_B(BUF, KT) {                                                        \
        GLDS(bT + (size_t)(KT) * 4096, &Bs[BUF][dstB]);                           \
        GLDS(bT + (size_t)(KT) * 4096 + 2048, &Bs[BUF][dstB + 2048]); }

    f32x4 acc[4][4] = {};

    // prologue: B(0)->buf0, A(0)->buf0 (regs->LDS), preload A(1)
    LOADA(0);
    STAGE_B(0, 0);
    WRITEA(0);
    LOADA(1);

    for (int kt = 0; kt < NT; ++kt) {
        const int cur = kt % 3;
        const int nxt = (kt + 1) % 3;
        STAGE_B(nxt, (kt + 1) & (NT - 1));   // wraps harmlessly on last iter
        WRITEA(nxt);        // regs A(kt+1); implicit vmcnt also certifies B(kt)
        LOADA((kt + 2) & (NT - 1));
        asm volatile("s_waitcnt lgkmcnt(0)\n\t"
                     "s_barrier" ::: "memory");

        bf16x8 af[4], bg[4];
#pragma unroll
        for (int mf = 0; mf < 4; ++mf)
            af[mf] = *reinterpret_cast<const bf16x8*>(
                &As[cur][((wm * 4 + mf) * 64 + laneSwz) * 8]);
#pragma unroll
        for (int nf = 0; nf < 4; ++nf)
            bg[nf] = *reinterpret_cast<const bf16x8*>(
                &Bs[cur][(wn >> 1) * 4096 + ((wn & 1) * 4 + nf) * 512 + lane * 8]);
        __builtin_amdgcn_s_setprio(1);
#pragma unroll
        for (int mf = 0; mf < 4; ++mf)
#pragma unroll
            for (int nf = 0; nf < 4; ++nf)
                acc[mf][nf] = __builtin_amdgcn_mfma_f32_16x16x32_bf16(
                    af[mf], bg[nf], acc[mf][nf], 0, 0, 0);
        __builtin_amdgcn_s_setprio(0);
        // no end-of-kt barrier: ring-3 re-write distance covers the hazard
    }

    // ---- epilogue 1: score -> exp(score); align write + rowsum atomic ----
    const float K2 = 2.8853900817779268f;
    const float LOG2E = 1.4426950408889634f;
    const float sb = score_b[0];
    const int g = lane >> 4;
    const int l15 = lane & 15;
    float kqb[4], swv[4];
#pragma unroll
    for (int nf = 0; nf < 4; ++nf) {
        const int d128 = (wn & 1) * 64 + nf * 16 + l15;
        kqb[nf] = qb_sm[(wn >> 1) * 128 + d128] * K2;
        swv[nf] = sw_sm[d128];
    }
    const float* leB = le + ((size_t)(b * 4096 + kk0) + wm * 64 + g * 4) * 128
                       + (wn & 1) * 64 + l15;

#pragma unroll
    for (int mf = 0; mf < 4; ++mf) {
        float lv[16];
#pragma unroll
        for (int jj = 0; jj < 4; ++jj)
#pragma unroll
            for (int nf = 0; nf < 4; ++nf)
                lv[jj * 4 + nf] = leB[(size_t)(mf * 16 + jj) * 128 + nf * 16];
#pragma unroll
        for (int jj = 0; jj < 4; ++jj) {
            const int row_l = wm * 64 + mf * 16 + g * 4 + jj;
            float sum = 0.f;
#pragma unroll
            for (int nf = 0; nf < 4; ++nf) {
                const float m = fmaf(K2, lv[jj * 4 + nf], kqb[nf]);
                const float tt = fmaf(K2, acc[mf][nf][jj], m);
                const float y = __builtin_amdgcn_exp2f(tt);
                const float r = fmaf(-2.0f, __builtin_amdgcn_rcpf(y + 1.0f), 1.0f);
                sum = fmaf(r, swv[nf], sum);
            }
            sum += __shfl_xor(sum, 1);
            sum += __shfl_xor(sum, 2);
            sum += __shfl_xor(sum, 4);
            sum += __shfl_xor(sum, 8);
            if (l15 == 0) partial[row_l][wn] = sum;
        }
    }
    __syncthreads();
    if (t < 256) {
        const int r = t >> 1, hh = t & 1;
        const float sc = partial[r][hh * 2] + partial[r][hh * 2 + 1] + sb;
        const float e = __builtin_amdgcn_exp2f(sc * LOG2E);
        align_out[(size_t)(b * 8 + hp * 2 + hh) * 4096 + kk0 + r] = e;  // raw
        e_sm[hh * 128 + r] = e;
        float s = e;
        s += __shfl_xor(s, 2);
        s += __shfl_xor(s, 4);
        s += __shfl_xor(s, 8);
        s += __shfl_xor(s, 16);
        s += __shfl_xor(s, 32);
        if ((lane >> 1) == 0)
            atomicAdd(&rowsum[b * 8 + hp * 2 + hh], s);
    }
    __syncthreads();

    // ---- epilogue 2: context GEMV: ctx[hh,d] += sum_r e[r] * value[r, col] ----
    {
        const int col = t & 255;       // 0..255 across both heads of the pair
        const int p = t >> 8;          // row parity
        const float* vcol = value + ((size_t)(b * 4096 + kk0 + p)) * 1024
                            + hp * 256 + col;
        const float* es = &e_sm[(col >> 7) * 128 + p];
        float acc2 = 0.f;
#pragma unroll 8
        for (int i = 0; i < 64; ++i)
            acc2 = fmaf(es[2 * i], vcol[(size_t)(2 * i) * 1024], acc2);
        float* comb = &partial[0][0];
        comb[t] = acc2;
        __syncthreads();
        if (t < 256) {
            const float tot = comb[t] + comb[t + 256];
            atomicAdd(&ctx_out[(size_t)(b * 8 + hp * 2 + (col >> 7)) * 128
                               + (col & 127)], tot);
        }
    }
}

// ---------- K4: finalize: align /= rowsum ; ctx /= rowsum ----------
__global__ __launch_bounds__(256) void finalize_kernel(
        float* __restrict__ align_o, float* __restrict__ ctx_out,
        const float* __restrict__ rowsum) {
    const int bid = blockIdx.x;
    const int t = threadIdx.x;
    if (bid < 512) {
        const int bh = bid >> 2;
        const float inv = 1.0f / rowsum[bh];
        float4* p = reinterpret_cast<float4*>(align_o + (size_t)bid * 1024);
        float4 v = p[t];
        v.x *= inv; v.y *= inv; v.z *= inv; v.w *= inv;
        p[t] = v;
    } else {
        const int i = (bid - 512) * 256 + t;   // 64 blocks x 256 = 16384
        ctx_out[i] *= 1.0f / rowsum[i >> 7];
    }
}

extern "C" void kernel_launch(void* const* d_in, const int* in_sizes, int n_in,
                              void* d_out, int out_size, void* d_ws, size_t ws_size,
                              hipStream_t stream) {
    const float* query   = (const float*)d_in[0];
    const float* key_in  = (const float*)d_in[1];
    const float* value   = (const float*)d_in[2];
    const float* pa      = (const float*)d_in[3];
    const float* conv_w  = (const float*)d_in[4];
    const float* conv_b  = (const float*)d_in[5];
    const float* w_u     = (const float*)d_in[6];
    const float* w_q     = (const float*)d_in[7];
    const float* w_v     = (const float*)d_in[8];
    const float* bias    = (const float*)d_in[9];
    const float* score_w = (const float*)d_in[10];
    const float* score_b = (const float*)d_in[11];

    float* out = (float*)d_out;
    float* ctx_out = out;                 // [128,128]
    float* align_out = out + 16384;       // [16,8,4096]

    char* ws = (char*)d_ws;
    const size_t OFF_Q    = 0;                        // 64 KB
    const size_t OFF_RS   = 65536;                    // 512 B (rowsum)
    const size_t OFF_WVT  = 66048;                    // 2 MB (tiled bf16)
    const size_t OFF_LE   = OFF_WVT + 2097152;        // 33.55 MB

    float* ws_q            = (float*)(ws + OFF_Q);
    float* ws_rs           = (float*)(ws + OFF_RS);
    unsigned short* ws_wvT = (unsigned short*)(ws + OFF_WVT);
    float* ws_le           = (float*)(ws + OFF_LE);

    hipLaunchKernelGGL(prep_kernel, dim3(897), dim3(256), 0, stream,
                       w_v, ws_wvT, query, w_q, ws_q,
                       pa, conv_w, conv_b, w_u, ws_le, ctx_out, ws_rs);
    hipLaunchKernelGGL(gemm_score_kernel, dim3(2048), dim3(512), 0, stream,
                       key_in, ws_wvT, ws_le, value, ws_q, bias, score_w, score_b,
                       align_out, ws_rs, ctx_out);
    hipLaunchKernelGGL(finalize_kernel, dim3(576), dim3(256), 0, stream,
                       align_out, ctx_out, ws_rs);
}